// Round 19
// baseline (319.794 us; speedup 1.0000x reference)
//
#include <hip/hip_runtime.h>
#include <hip/hip_bf16.h>

#define NEG_SLOPE 0.2f
#define BW  128              // bucket width in dst nodes
#define BSH 7

__device__ __forceinline__ float elu1f(float v) {
    return v > 0.f ? v : expm1f(v);
}
__device__ __forceinline__ float bf2f(ushort u) {
    return __uint_as_float(((unsigned)u) << 16);
}
__device__ __forceinline__ ushort f2bf(float f) {
    return __bfloat16_as_ushort(__float2bfloat16(f));
}
__device__ __forceinline__ unsigned fflip(float f) {
    unsigned u = __float_as_uint(f);
    return (u & 0x80000000u) ? ~u : (u | 0x80000000u);
}
__device__ __forceinline__ float funflip(unsigned u) {
    u = (u & 0x80000000u) ? (u & 0x7FFFFFFFu) : ~u;
    return __uint_as_float(u);
}

// ================= Bucketed CSR build (by dst) =================
__global__ __launch_bounds__(256) void k_bcount(
    const int* __restrict__ ei, int E, int Et, int nbk, int* __restrict__ bcnt)
{
    __shared__ int h[512];
    for (int i = threadIdx.x; i < nbk; i += 256) h[i] = 0;
    __syncthreads();
    const int start = blockIdx.x * 4096;
    const int end   = min(start + 4096, Et);
    for (int i = start + threadIdx.x; i < end; i += 256) {
        int d = (i < E) ? ei[E + i] : i - E;
        atomicAdd(&h[d >> BSH], 1);
    }
    __syncthreads();
    for (int i = threadIdx.x; i < nbk; i += 256)
        if (h[i]) atomicAdd(&bcnt[i], h[i]);
}

// + folded graph-boundary search (was k_bounds)
__global__ __launch_bounds__(512) void k_bscan(
    const int* __restrict__ bcnt, int nbk, int Et,
    int* __restrict__ bbase, int* __restrict__ bcur,
    const int* __restrict__ batch, int* __restrict__ gbound, int N, int G)
{
    __shared__ int s[512];
    int v = (threadIdx.x < nbk) ? bcnt[threadIdx.x] : 0;
    s[threadIdx.x] = v;
    __syncthreads();
#pragma unroll
    for (int off = 1; off < 512; off <<= 1) {
        int t = (threadIdx.x >= off) ? s[threadIdx.x - off] : 0;
        __syncthreads();
        s[threadIdx.x] += t;
        __syncthreads();
    }
    if (threadIdx.x < nbk) {
        int ex = s[threadIdx.x] - v;
        bbase[threadIdx.x] = ex;
        bcur[threadIdx.x]  = ex;
    }
    if (threadIdx.x == 0) bbase[nbk] = Et;
    if (threadIdx.x <= (unsigned)G) {
        int target = threadIdx.x;
        int lo = 0, hi = N;
        while (lo < hi) { int mid = (lo + hi) >> 1; if (batch[mid] < target) lo = mid + 1; else hi = mid; }
        gbound[threadIdx.x] = lo;
    }
}

// ebuk entry: (d & 127) << 25 | src   (src < 2^25)
__global__ __launch_bounds__(256) void k_bscatter(
    const int* __restrict__ ei, int E, int Et, int nbk,
    int* __restrict__ bcur, unsigned* __restrict__ ebuk)
{
    __shared__ int h[512];
    __shared__ int cur[512];
    for (int i = threadIdx.x; i < nbk; i += 256) h[i] = 0;
    __syncthreads();
    const int start = blockIdx.x * 4096;
    const int end   = min(start + 4096, Et);
    for (int i = start + threadIdx.x; i < end; i += 256) {
        int d = (i < E) ? ei[E + i] : i - E;
        atomicAdd(&h[d >> BSH], 1);
    }
    __syncthreads();
    for (int i = threadIdx.x; i < nbk; i += 256)
        cur[i] = h[i] ? atomicAdd(&bcur[i], h[i]) : 0;
    __syncthreads();
    for (int i = start + threadIdx.x; i < end; i += 256) {
        int s, d;
        if (i < E) { s = ei[i]; d = ei[E + i]; } else { s = i - E; d = s; }
        int p = atomicAdd(&cur[d >> BSH], 1);
        ebuk[p] = ((unsigned)(d & (BW - 1)) << 25) | (unsigned)s;
    }
}

// ===== Fused: per-bucket deg + local scan -> rowp, then place edges -> esrc =====
__global__ __launch_bounds__(256) void k_csr(
    const unsigned* __restrict__ ebuk, const int* __restrict__ bbase,
    int N, int Et, int* __restrict__ rowp, int* __restrict__ esrc)
{
    const int b = blockIdx.x;
    __shared__ int cnt[BW];
    __shared__ int pre[BW];
    __shared__ int lcur[BW];
    if (threadIdx.x < BW) cnt[threadIdx.x] = 0;
    __syncthreads();
    const int e0 = bbase[b], e1 = bbase[b + 1];
    for (int i = e0 + threadIdx.x; i < e1; i += 256)
        atomicAdd(&cnt[ebuk[i] >> 25], 1);
    __syncthreads();
    if (threadIdx.x < BW) pre[threadIdx.x] = cnt[threadIdx.x];
    __syncthreads();
#pragma unroll
    for (int off = 1; off < BW; off <<= 1) {
        int v = (threadIdx.x < BW && threadIdx.x >= off) ? pre[threadIdx.x - off] : 0;
        __syncthreads();
        if (threadIdx.x < BW) pre[threadIdx.x] += v;
        __syncthreads();
    }
    const int d0 = b << BSH;
    if (threadIdx.x < BW) {
        int r = e0 + pre[threadIdx.x] - cnt[threadIdx.x];   // exclusive
        int d = d0 + threadIdx.x;
        if (d < N) rowp[d] = r;
        lcur[threadIdx.x] = r;
    }
    if (b == 0 && threadIdx.x == 0) rowp[N] = Et;
    __syncthreads();
    for (int i = e0 + threadIdx.x; i < e1; i += 256) {
        unsigned e = ebuk[i];
        int p = atomicAdd(&lcur[e >> 25], 1);
        esrc[p] = (int)(e & 0x1FFFFFFu);
    }
}

// ---------------- GEMM1: h1(bf16) = x @ W1 (128->128), 4x4 blocking ----------------
__global__ __launch_bounds__(256) void k_gemm1(
    const float* __restrict__ x, const float* __restrict__ W,
    const float* __restrict__ att_s, const float* __restrict__ att_d,
    ushort* __restrict__ h1, float* __restrict__ asT, float* __restrict__ ad1,
    unsigned* __restrict__ gmaxu, int N)
{
    __shared__ __align__(16) float sW[16][128];   // 8 KB
    __shared__ __align__(16) float sX[32][16];    // 2 KB
    __shared__ unsigned smax[4];
    const int t  = threadIdx.x;
    const int c4 = t & 31;             // col group (cols c4*4 .. c4*4+3)
    const int rg = t >> 5;             // row group (rows rg*4 .. rg*4+3)
    const int row0 = blockIdx.x * 32;
    const float4* W4 = (const float4*)W;   // W row = 32 float4

    if (t < 4) smax[t] = 0;            // first loop barrier makes this visible

    float4 acc[4];
#pragma unroll
    for (int i = 0; i < 4; i++) acc[i] = {0.f, 0.f, 0.f, 0.f};

    for (int k0 = 0; k0 < 128; k0 += 16) {
        __syncthreads();
#pragma unroll
        for (int j = 0; j < 2; j++) {
            int idx = j * 256 + t;                 // 0..511
            int r = idx >> 5, cc = idx & 31;
            *(float4*)&sW[r][cc * 4] = W4[(k0 + r) * 32 + cc];
        }
        if (t < 128) {
            int r = t >> 2, q = t & 3;
            int row = row0 + r;
            float4 v = {0.f, 0.f, 0.f, 0.f};
            if (row < N) v = *(const float4*)&x[(long long)row * 128 + k0 + q * 4];
            *(float4*)&sX[r][q * 4] = v;
        }
        __syncthreads();
#pragma unroll
        for (int g = 0; g < 4; g++) {
            const int kk = g * 4;
            const float4 w0 = *(const float4*)&sW[kk + 0][c4 * 4];
            const float4 w1 = *(const float4*)&sW[kk + 1][c4 * 4];
            const float4 w2 = *(const float4*)&sW[kk + 2][c4 * 4];
            const float4 w3 = *(const float4*)&sW[kk + 3][c4 * 4];
#pragma unroll
            for (int i = 0; i < 4; i++) {
                const float4 xv = *(const float4*)&sX[rg * 4 + i][kk];  // broadcast
                acc[i].x = fmaf(xv.x, w0.x, acc[i].x);
                acc[i].y = fmaf(xv.x, w0.y, acc[i].y);
                acc[i].z = fmaf(xv.x, w0.z, acc[i].z);
                acc[i].w = fmaf(xv.x, w0.w, acc[i].w);
                acc[i].x = fmaf(xv.y, w1.x, acc[i].x);
                acc[i].y = fmaf(xv.y, w1.y, acc[i].y);
                acc[i].z = fmaf(xv.y, w1.z, acc[i].z);
                acc[i].w = fmaf(xv.y, w1.w, acc[i].w);
                acc[i].x = fmaf(xv.z, w2.x, acc[i].x);
                acc[i].y = fmaf(xv.z, w2.y, acc[i].y);
                acc[i].z = fmaf(xv.z, w2.z, acc[i].z);
                acc[i].w = fmaf(xv.z, w2.w, acc[i].w);
                acc[i].x = fmaf(xv.w, w3.x, acc[i].x);
                acc[i].y = fmaf(xv.w, w3.y, acc[i].y);
                acc[i].z = fmaf(xv.w, w3.z, acc[i].z);
                acc[i].w = fmaf(xv.w, w3.w, acc[i].w);
            }
        }
    }

    const float4 avs = *(const float4*)&att_s[c4 * 4];
    const float4 avd = *(const float4*)&att_d[c4 * 4];
    const int hd = c4 >> 3;                        // head of this thread's 4 cols
    float lmax = -INFINITY;
#pragma unroll
    for (int i = 0; i < 4; i++) {
        int row = row0 + rg * 4 + i;
        if (row < N) {
            ushort4 hb;
            hb.x = f2bf(acc[i].x); hb.y = f2bf(acc[i].y);
            hb.z = f2bf(acc[i].z); hb.w = f2bf(acc[i].w);
            *(ushort4*)&h1[(long long)row * 128 + c4 * 4] = hb;
            float s = acc[i].x * avs.x + acc[i].y * avs.y + acc[i].z * avs.z + acc[i].w * avs.w;
            float d = acc[i].x * avd.x + acc[i].y * avd.y + acc[i].z * avd.z + acc[i].w * avd.w;
#pragma unroll
            for (int off = 4; off > 0; off >>= 1) {    // reduce over 8 col-threads of head
                s += __shfl_xor(s, off, 64);
                d += __shfl_xor(d, off, 64);
            }
            if ((c4 & 7) == 0) {
                asT[(unsigned)hd * (unsigned)N + row] = s;
                ad1[row * 4 + hd] = d;
                lmax = fmaxf(lmax, s);
            }
        }
    }
    if ((c4 & 7) == 0) atomicMax(&smax[hd], fflip(lmax));
    __syncthreads();
    if (t < 4 && smax[t]) atomicMax(&gmaxu[t], smax[t]);
}

// ---------------- GEMM2: h2(bf16) = elu(out1(bf16)+b1) @ W2 (128->32) ----------------
__global__ __launch_bounds__(256) void k_gemm2(
    const ushort* __restrict__ xin, const float* __restrict__ W,
    const float* __restrict__ b1,
    const float* __restrict__ att_s, const float* __restrict__ att_d,
    ushort* __restrict__ h2, float* __restrict__ as2, float* __restrict__ ad2,
    unsigned* __restrict__ gmax2u, int N)
{
    __shared__ __align__(16) float sW[16][32];    // 2 KB
    __shared__ __align__(16) float sX[128][16];   // 8 KB
    __shared__ unsigned smax1;
    const int t  = threadIdx.x;
    const int c4 = t & 7;              // col group (cols c4*4 .. c4*4+3)
    const int rg = t >> 3;             // row group (rows rg*4 .. rg*4+3)
    const int row0 = blockIdx.x * 128;
    const float4* W4 = (const float4*)W;          // W row = 8 float4

    if (t == 0) smax1 = 0;

    float4 acc[4];
#pragma unroll
    for (int i = 0; i < 4; i++) acc[i] = {0.f, 0.f, 0.f, 0.f};

    for (int k0 = 0; k0 < 128; k0 += 16) {
        __syncthreads();
        if (t < 128) {                 // stage W tile: 16x32 = 128 float4
            int r = t >> 3, cc = t & 7;
            *(float4*)&sW[r][cc * 4] = W4[(k0 + r) * 8 + cc];
        }
#pragma unroll
        for (int j = 0; j < 2; j++) {  // stage X tile: 128x16 = 512 ushort4-loads
            int idx = j * 256 + t;
            int r = idx >> 2, q = idx & 3;
            int row = row0 + r;
            float4 v = {0.f, 0.f, 0.f, 0.f};
            if (row < N) {
                const ushort4 uv = *(const ushort4*)&xin[(long long)row * 128 + k0 + q * 4];
                float4 b = *(const float4*)&b1[k0 + q * 4];
                v.x = elu1f(bf2f(uv.x) + b.x); v.y = elu1f(bf2f(uv.y) + b.y);
                v.z = elu1f(bf2f(uv.z) + b.z); v.w = elu1f(bf2f(uv.w) + b.w);
            }
            *(float4*)&sX[r][q * 4] = v;
        }
        __syncthreads();
#pragma unroll
        for (int g = 0; g < 4; g++) {
            const int kk = g * 4;
            const float4 w0 = *(const float4*)&sW[kk + 0][c4 * 4];
            const float4 w1 = *(const float4*)&sW[kk + 1][c4 * 4];
            const float4 w2 = *(const float4*)&sW[kk + 2][c4 * 4];
            const float4 w3 = *(const float4*)&sW[kk + 3][c4 * 4];
#pragma unroll
            for (int i = 0; i < 4; i++) {
                const float4 xv = *(const float4*)&sX[rg * 4 + i][kk];
                acc[i].x = fmaf(xv.x, w0.x, acc[i].x);
                acc[i].y = fmaf(xv.x, w0.y, acc[i].y);
                acc[i].z = fmaf(xv.x, w0.z, acc[i].z);
                acc[i].w = fmaf(xv.x, w0.w, acc[i].w);
                acc[i].x = fmaf(xv.y, w1.x, acc[i].x);
                acc[i].y = fmaf(xv.y, w1.y, acc[i].y);
                acc[i].z = fmaf(xv.y, w1.z, acc[i].z);
                acc[i].w = fmaf(xv.y, w1.w, acc[i].w);
                acc[i].x = fmaf(xv.z, w2.x, acc[i].x);
                acc[i].y = fmaf(xv.z, w2.y, acc[i].y);
                acc[i].z = fmaf(xv.z, w2.z, acc[i].z);
                acc[i].w = fmaf(xv.z, w2.w, acc[i].w);
                acc[i].x = fmaf(xv.w, w3.x, acc[i].x);
                acc[i].y = fmaf(xv.w, w3.y, acc[i].y);
                acc[i].z = fmaf(xv.w, w3.z, acc[i].z);
                acc[i].w = fmaf(xv.w, w3.w, acc[i].w);
            }
        }
    }

    const float4 avs = *(const float4*)&att_s[c4 * 4];
    const float4 avd = *(const float4*)&att_d[c4 * 4];
    float lmax = -INFINITY;
#pragma unroll
    for (int i = 0; i < 4; i++) {
        int row = row0 + rg * 4 + i;
        if (row < N) {
            ushort4 hb;
            hb.x = f2bf(acc[i].x); hb.y = f2bf(acc[i].y);
            hb.z = f2bf(acc[i].z); hb.w = f2bf(acc[i].w);
            *(ushort4*)&h2[(long long)row * 32 + c4 * 4] = hb;
            float s = acc[i].x * avs.x + acc[i].y * avs.y + acc[i].z * avs.z + acc[i].w * avs.w;
            float d = acc[i].x * avd.x + acc[i].y * avd.y + acc[i].z * avd.z + acc[i].w * avd.w;
#pragma unroll
            for (int off = 4; off > 0; off >>= 1) {    // reduce over 8 col-threads
                s += __shfl_xor(s, off, 64);
                d += __shfl_xor(d, off, 64);
            }
            if (c4 == 0) {
                as2[row] = s; ad2[row] = d;
                lmax = fmaxf(lmax, s);
            }
        }
    }
    if (c4 == 0) atomicMax(&smax1, fflip(lmax));
    __syncthreads();
    if (t == 0 && smax1) atomicMax(&gmax2u[0], smax1);
}

// ========== Fused GAT aggregation, layer 1 (H=4, C=32): one wave per dst ==========
__global__ __launch_bounds__(256) void k_agg1(
    const int* __restrict__ row, const int* __restrict__ esrc,
    const float* __restrict__ asT, const float* __restrict__ ad,  // [4][N], [N][4]
    const unsigned* __restrict__ gmaxu,                           // [4] flipped
    const ushort* __restrict__ h,                                 // [N][128] bf16
    ushort* __restrict__ out, int N)                              // [N][128] bf16
{
    const int lane = threadIdx.x & 63;
    const int wid  = threadIdx.x >> 6;
    const int n = blockIdx.x * 4 + wid;
    if (n >= N) return;
    const int e0 = row[n], e1 = row[n + 1];

    const float4 ad4 = *(const float4*)&ad[n * 4];
    const int half = lane >> 5;
    const int l    = lane & 31;                 // 4 cols per lane: l*4..l*4+3
    const int hd   = l >> 3;                    // head of those cols
    const float adh = hd == 0 ? ad4.x : hd == 1 ? ad4.y : hd == 2 ? ad4.z : ad4.w;
    float mh = funflip(gmaxu[hd]) + adh;
    mh = mh >= 0.f ? mh : NEG_SLOPE * mh;

    const float* asH = asT + (unsigned)hd * (unsigned)N;
    const unsigned lofs = (unsigned)(l * 4);
    float4 acc = {0.f, 0.f, 0.f, 0.f};
    float wsum = 0.f;
    for (int base = e0; base < e1; base += 8) {
        const int eA = base + half,     eB = base + 2 + half;
        const int eC = base + 4 + half, eD = base + 6 + half;
        const bool vA = eA < e1, vB = eB < e1, vC = eC < e1, vD = eD < e1;
        const int sA = vA ? esrc[eA] : 0;
        const int sB = vB ? esrc[eB] : 0;
        const int sC = vC ? esrc[eC] : 0;
        const int sD = vD ? esrc[eD] : 0;
        const float aA = asH[sA];
        const float aB = asH[sB];
        const float aC = asH[sC];
        const float aD = asH[sD];
        const ushort4 hA = *(const ushort4*)&h[(unsigned)sA * 128u + lofs];
        const ushort4 hB = *(const ushort4*)&h[(unsigned)sB * 128u + lofs];
        const ushort4 hC = *(const ushort4*)&h[(unsigned)sC * 128u + lofs];
        const ushort4 hD = *(const ushort4*)&h[(unsigned)sD * 128u + lofs];

        float evA = aA + adh;
        evA = evA >= 0.f ? evA : NEG_SLOPE * evA;
        const float wA = vA ? __expf(evA - mh) : 0.f;
        float evB = aB + adh;
        evB = evB >= 0.f ? evB : NEG_SLOPE * evB;
        const float wB = vB ? __expf(evB - mh) : 0.f;
        float evC = aC + adh;
        evC = evC >= 0.f ? evC : NEG_SLOPE * evC;
        const float wC = vC ? __expf(evC - mh) : 0.f;
        float evD = aD + adh;
        evD = evD >= 0.f ? evD : NEG_SLOPE * evD;
        const float wD = vD ? __expf(evD - mh) : 0.f;

        acc.x = fmaf(wA, bf2f(hA.x), acc.x);
        acc.y = fmaf(wA, bf2f(hA.y), acc.y);
        acc.z = fmaf(wA, bf2f(hA.z), acc.z);
        acc.w = fmaf(wA, bf2f(hA.w), acc.w);
        acc.x = fmaf(wB, bf2f(hB.x), acc.x);
        acc.y = fmaf(wB, bf2f(hB.y), acc.y);
        acc.z = fmaf(wB, bf2f(hB.z), acc.z);
        acc.w = fmaf(wB, bf2f(hB.w), acc.w);
        acc.x = fmaf(wC, bf2f(hC.x), acc.x);
        acc.y = fmaf(wC, bf2f(hC.y), acc.y);
        acc.z = fmaf(wC, bf2f(hC.z), acc.z);
        acc.w = fmaf(wC, bf2f(hC.w), acc.w);
        acc.x = fmaf(wD, bf2f(hD.x), acc.x);
        acc.y = fmaf(wD, bf2f(hD.y), acc.y);
        acc.z = fmaf(wD, bf2f(hD.z), acc.z);
        acc.w = fmaf(wD, bf2f(hD.w), acc.w);
        wsum += (wA + wB) + (wC + wD);
    }
    acc.x += __shfl_xor(acc.x, 32, 64);
    acc.y += __shfl_xor(acc.y, 32, 64);
    acc.z += __shfl_xor(acc.z, 32, 64);
    acc.w += __shfl_xor(acc.w, 32, 64);
    wsum  += __shfl_xor(wsum, 32, 64);

    if (half == 0) {
        const float inv = 1.f / (wsum + 1e-16f);
        ushort4 ob;
        ob.x = f2bf(acc.x * inv); ob.y = f2bf(acc.y * inv);
        ob.z = f2bf(acc.z * inv); ob.w = f2bf(acc.w * inv);
        *(ushort4*)&out[(long long)n * 128 + l * 4] = ob;
    }
}

// ========== Fused GAT aggregation, layer 2 + gate MLP (elu hoisted) ==========
// One wave per dst (valid-guarded, no early return: block max needs syncthreads).
// After the butterfly reduce every lane holds the full row; lanes' float4 covers
// cols (lane&7)*4.. +3. elu is applied ONCE (4 wave-ops), then 32 x {shfl,fma}.
__global__ __launch_bounds__(256) void k_agg2(
    const int* __restrict__ row, const int* __restrict__ esrc,
    const float* __restrict__ as, const float* __restrict__ ad,   // [N]
    const unsigned* __restrict__ gmax2u,                          // [1] flipped
    const ushort* __restrict__ h,                                 // [N][32] bf16
    const float* __restrict__ b2,
    const float* __restrict__ gw1, const float* __restrict__ gb1,
    const float* __restrict__ gw2, const float* __restrict__ gb2,
    float* __restrict__ out, float* __restrict__ gate,
    unsigned* __restrict__ gGu, int N)                            // gGu[8]: gate maxes
{
    __shared__ unsigned sgmax;
    const int lane = threadIdx.x & 63;
    const int wid  = threadIdx.x >> 6;
    const int n = blockIdx.x * 4 + wid;
    const bool valid = n < N;
    if (threadIdx.x == 0) sgmax = 0;

    const int e0 = valid ? row[n] : 0;
    const int e1 = valid ? row[n + 1] : 0;
    const float adv = valid ? ad[n] : 0.f;
    float m = funflip(gmax2u[0]) + adv;
    m = m >= 0.f ? m : NEG_SLOPE * m;

    const int g  = lane >> 3;                    // edge slot 0..7
    const int l8 = lane & 7;                     // 4 cols: l8*4..l8*4+3
    const unsigned lofs = (unsigned)(l8 * 4);
    float4 acc = {0.f, 0.f, 0.f, 0.f};
    float wsum = 0.f;
    for (int base = e0; base < e1; base += 32) {
        const int eA = base + g,      eB = base + 8 + g;
        const int eC = base + 16 + g, eD = base + 24 + g;
        const bool vA = eA < e1, vB = eB < e1, vC = eC < e1, vD = eD < e1;
        const int sA = vA ? esrc[eA] : 0;
        const int sB = vB ? esrc[eB] : 0;
        const int sC = vC ? esrc[eC] : 0;
        const int sD = vD ? esrc[eD] : 0;
        const float asA = as[sA], asB = as[sB], asC = as[sC], asD = as[sD];
        const ushort4 hA = *(const ushort4*)&h[(unsigned)sA * 32u + lofs];
        const ushort4 hB = *(const ushort4*)&h[(unsigned)sB * 32u + lofs];
        const ushort4 hC = *(const ushort4*)&h[(unsigned)sC * 32u + lofs];
        const ushort4 hD = *(const ushort4*)&h[(unsigned)sD * 32u + lofs];

        float evA = asA + adv; evA = evA >= 0.f ? evA : NEG_SLOPE * evA;
        const float wA = vA ? __expf(evA - m) : 0.f;
        float evB = asB + adv; evB = evB >= 0.f ? evB : NEG_SLOPE * evB;
        const float wB = vB ? __expf(evB - m) : 0.f;
        float evC = asC + adv; evC = evC >= 0.f ? evC : NEG_SLOPE * evC;
        const float wC = vC ? __expf(evC - m) : 0.f;
        float evD = asD + adv; evD = evD >= 0.f ? evD : NEG_SLOPE * evD;
        const float wD = vD ? __expf(evD - m) : 0.f;

        acc.x = fmaf(wA, bf2f(hA.x), acc.x);
        acc.y = fmaf(wA, bf2f(hA.y), acc.y);
        acc.z = fmaf(wA, bf2f(hA.z), acc.z);
        acc.w = fmaf(wA, bf2f(hA.w), acc.w);
        acc.x = fmaf(wB, bf2f(hB.x), acc.x);
        acc.y = fmaf(wB, bf2f(hB.y), acc.y);
        acc.z = fmaf(wB, bf2f(hB.z), acc.z);
        acc.w = fmaf(wB, bf2f(hB.w), acc.w);
        acc.x = fmaf(wC, bf2f(hC.x), acc.x);
        acc.y = fmaf(wC, bf2f(hC.y), acc.y);
        acc.z = fmaf(wC, bf2f(hC.z), acc.z);
        acc.w = fmaf(wC, bf2f(hC.w), acc.w);
        acc.x = fmaf(wD, bf2f(hD.x), acc.x);
        acc.y = fmaf(wD, bf2f(hD.y), acc.y);
        acc.z = fmaf(wD, bf2f(hD.z), acc.z);
        acc.w = fmaf(wD, bf2f(hD.w), acc.w);
        wsum += (wA + wB) + (wC + wD);
    }
#pragma unroll
    for (int off = 8; off < 64; off <<= 1) {
        acc.x += __shfl_xor(acc.x, off, 64);
        acc.y += __shfl_xor(acc.y, off, 64);
        acc.z += __shfl_xor(acc.z, off, 64);
        acc.w += __shfl_xor(acc.w, off, 64);
        wsum  += __shfl_xor(wsum, off, 64);
    }
    const float inv = 1.f / (wsum + 1e-16f);
    float4 o; o.x = acc.x * inv; o.y = acc.y * inv; o.z = acc.z * inv; o.w = acc.w * inv;
    if (valid && lane < 8) {
        *(float4*)&out[(long long)n * 32 + lane * 4] = o;
    }

    // ---- fused gate MLP (elu hoisted out of the loop) ----
    float4 eo;
    eo.x = elu1f(o.x + b2[l8 * 4 + 0]);
    eo.y = elu1f(o.y + b2[l8 * 4 + 1]);
    eo.z = elu1f(o.z + b2[l8 * 4 + 2]);
    eo.w = elu1f(o.w + b2[l8 * 4 + 3]);
    const int c = lane & 31;
    float t1 = gb1[c];
#pragma unroll
    for (int k = 0; k < 32; k++) {
        float comp;
        if ((k & 3) == 0) comp = eo.x;
        else if ((k & 3) == 1) comp = eo.y;
        else if ((k & 3) == 2) comp = eo.z;
        else comp = eo.w;
        float hk = __shfl(comp, k >> 2, 64);       // lane k>>2 holds cols k (elu'd)
        t1 = fmaf(hk, gw1[k * 32 + c], t1);
    }
    t1 = fmaxf(t1, 0.f);
    float gv = t1 * gw2[c];
#pragma unroll
    for (int off = 16; off > 0; off >>= 1) gv += __shfl_xor(gv, off, 32);
    const float gval = gv + gb2[0];
    if (valid && lane == 0) {
        gate[n] = gval;
        atomicMax(&sgmax, fflip(gval));            // LDS atomic, 4 per block
    }
    __syncthreads();
    if (threadIdx.x == 0 && sgmax) atomicMax(&gGu[blockIdx.x & 7], sgmax);
}

// ========== Pool stage 2: per-chunk partial weighted sums (no atomics) ==========
// Uses the GLOBAL gate max (8 slots) as the shared softmax bound for all graphs.
__global__ __launch_bounds__(256) void k_pool3(
    const float* __restrict__ out2, const float* __restrict__ b2,
    const float* __restrict__ gate, const int* __restrict__ gbound,
    const unsigned* __restrict__ gGu, float* __restrict__ partials)
{
    const int g  = blockIdx.x >> 3;
    const int ch = blockIdx.x & 7;
    const int s0 = gbound[g], s1 = gbound[g + 1];
    const int len = s1 - s0;
    const int c0 = s0 + (int)(((long long)len * ch) >> 3);
    const int c1 = s0 + (int)(((long long)len * (ch + 1)) >> 3);

    unsigned mu = gGu[0];
#pragma unroll
    for (int i = 1; i < 8; i++) mu = max(mu, gGu[i]);
    const float gm = funflip(mu);

    const int c   = threadIdx.x & 31;
    const int grp = threadIdx.x >> 5;
    const float bc = b2[c];

    __shared__ float sacc[8][32];
    __shared__ float swsum[8];

    float acc = 0.f, wsum = 0.f;
    for (int n = c0 + grp; n < c1; n += 8) {
        float v = elu1f(out2[(long long)n * 32 + c] + bc);
        float ge = __expf(gate[n] - gm);
        acc = fmaf(ge, v, acc);
        wsum += ge;
    }
    sacc[grp][c] = acc;
    if (c == 0) swsum[grp] = wsum;
    __syncthreads();

    if (grp == 0) {
        float a = 0.f, wtot = 0.f;
#pragma unroll
        for (int i = 0; i < 8; i++) { a += sacc[i][c]; wtot += swsum[i]; }
        partials[(long long)blockIdx.x * 33 + c] = a;
        if (c == 0) partials[(long long)blockIdx.x * 33 + 32] = wtot;
    }
}

// ========== Pool stage 3: reduce 8 partials per graph, divide, write out ==========
__global__ __launch_bounds__(256) void k_pool4(
    const float* __restrict__ partials, float* __restrict__ out)
{
    const int g   = blockIdx.x;
    const int c   = threadIdx.x & 31;
    const int p   = threadIdx.x >> 5;

    __shared__ float sacc[8][32];
    __shared__ float swsum[8];

    sacc[p][c] = partials[(long long)(g * 8 + p) * 33 + c];
    if (c == 0) swsum[p] = partials[(long long)(g * 8 + p) * 33 + 32];
    __syncthreads();

    if (p == 0) {
        float a = 0.f, wtot = 0.f;
#pragma unroll
        for (int i = 0; i < 8; i++) { a += sacc[i][c]; wtot += swsum[i]; }
        out[g * 32 + c] = a / (wtot + 1e-16f);
    }
}

extern "C" void kernel_launch(void* const* d_in, const int* in_sizes, int n_in,
                              void* d_out, int out_size, void* d_ws, size_t ws_size,
                              hipStream_t stream)
{
    const float* x    = (const float*)d_in[0];
    const int*   ei   = (const int*)d_in[1];
    const int*   batch= (const int*)d_in[2];
    const float* W1   = (const float*)d_in[3];
    const float* as1w = (const float*)d_in[4];
    const float* ad1w = (const float*)d_in[5];
    const float* b1   = (const float*)d_in[6];
    const float* W2   = (const float*)d_in[7];
    const float* as2w = (const float*)d_in[8];
    const float* ad2w = (const float*)d_in[9];
    const float* b2   = (const float*)d_in[10];
    const float* gw1  = (const float*)d_in[11];
    const float* gb1  = (const float*)d_in[12];
    const float* gw2  = (const float*)d_in[13];
    const float* gb2  = (const float*)d_in[14];

    const int N  = in_sizes[2];
    const int E  = in_sizes[1] / 2;
    const int Et = E + N;
    const int G  = 64;
    const int nbk   = (N + BW - 1) >> BSH;   // 391 buckets (<=512)
    const int nchk  = (Et + 4095) / 4096;    // bucket-build chunks
    const int nblk1 = (N + 31) / 32;         // gemm1 blocks
    const int nblk2 = (N + 127) / 128;       // gemm2 blocks

    float* ws = (float*)d_ws;
    size_t o = 0;
    unsigned* ebuk = (unsigned*)(ws + o); o += (size_t)Et * 2;  // u32 used; +Et pad keeps h1 at the round-14 offset (measured lower FETCH)
    ushort* h1 = (ushort*)(ws + o); o += (size_t)N * 64;   // bf16 [N][128]
    ushort* out1 = (ushort*)(ws + o); o += (size_t)N * 64; // bf16 [N][128]
    ushort* h2 = (ushort*)(ws + o); o += (size_t)N * 16;   // bf16 [N][32]
    float* out2 = ws + o; o += (size_t)N * 32;
    float* asT1 = ws + o; o += (size_t)N * 4;              // [4][N] transposed
    float* a_d1 = ws + o; o += (size_t)N * 4;
    float* a_s2 = ws + o; o += (size_t)N;
    float* a_d2 = ws + o; o += (size_t)N;
    float* gate = ws + o; o += (size_t)N;
    int*   rowp = (int*)(ws + o); o += (size_t)N + 1;
    int*   esrc = (int*)(ws + o); o += (size_t)Et;
    int*   bbase= (int*)(ws + o); o += (size_t)nbk + 1;
    int*   bcur = (int*)(ws + o); o += (size_t)nbk;        // init by k_bscan
    int*   gbound = (int*)(ws + o); o += G + 1;
    float* partials = ws + o; o += (size_t)G * 8 * 33;
    // ---- zeroed region (one memset): bcnt + gmaxu + gmax2u + gGu ----
    size_t zstart = o;
    int*      bcnt   = (int*)(ws + o); o += (size_t)nbk;
    unsigned* gmaxu  = (unsigned*)(ws + o); o += 4;        // layer-1 head maxes (flipped)
    unsigned* gmax2u = (unsigned*)(ws + o); o += 4;        // layer-2 max (flipped)
    unsigned* gGu    = (unsigned*)(ws + o); o += 8;        // gate maxes (flipped, 8 slots)
    size_t zbytes = (o - zstart) * sizeof(float);

    hipMemsetAsync(ws + zstart, 0, zbytes, stream);

    // ---- bucketed CSR build (shared by both layers) + graph bounds ----
    k_bcount  <<<nchk, 256, 0, stream>>>(ei, E, Et, nbk, bcnt);
    k_bscan   <<<1, 512, 0, stream>>>(bcnt, nbk, Et, bbase, bcur, batch, gbound, N, G);
    k_bscatter<<<nchk, 256, 0, stream>>>(ei, E, Et, nbk, bcur, ebuk);
    k_csr     <<<nbk, 256, 0, stream>>>(ebuk, bbase, N, Et, rowp, esrc);

    // ---- GAT layer 1 ----
    k_gemm1<<<nblk1, 256, 0, stream>>>(x, W1, as1w, ad1w, h1, asT1, a_d1, gmaxu, N);
    k_agg1 <<<(N + 3) / 4, 256, 0, stream>>>(rowp, esrc, asT1, a_d1, gmaxu, h1, out1, N);

    // ---- GAT layer 2 (elu(out1+b1) fused into gemm2 load) ----
    k_gemm2<<<nblk2, 256, 0, stream>>>(out1, W2, b1, as2w, ad2w, h2, a_s2, a_d2, gmax2u, N);
    k_agg2 <<<(N + 3) / 4, 256, 0, stream>>>(rowp, esrc, a_s2, a_d2, gmax2u, h2,
                                             b2, gw1, gb1, gw2, gb2, out2, gate, gGu, N);

    // ---- attentional pooling: partial sums (global gate-max bound), final reduce ----
    k_pool3<<<G * 8, 256, 0, stream>>>(out2, b2, gate, gbound, gGu, partials);
    k_pool4<<<G, 256, 0, stream>>>(partials, (float*)d_out);
}

// Round 20
// 204.981 us; speedup vs baseline: 1.5601x; 1.5601x over previous
//
#include <hip/hip_runtime.h>
#include <hip/hip_bf16.h>

#define NEG_SLOPE 0.2f
#define BW  128              // bucket width in dst nodes
#define BSH 7

__device__ __forceinline__ float elu1f(float v) {
    return v > 0.f ? v : expm1f(v);
}
__device__ __forceinline__ float bf2f(ushort u) {
    return __uint_as_float(((unsigned)u) << 16);
}
__device__ __forceinline__ ushort f2bf(float f) {
    return __bfloat16_as_ushort(__float2bfloat16(f));
}
__device__ __forceinline__ unsigned fflip(float f) {
    unsigned u = __float_as_uint(f);
    return (u & 0x80000000u) ? ~u : (u | 0x80000000u);
}
__device__ __forceinline__ float funflip(unsigned u) {
    u = (u & 0x80000000u) ? (u & 0x7FFFFFFFu) : ~u;
    return __uint_as_float(u);
}

// ================= Bucketed CSR build (by dst) =================
__global__ __launch_bounds__(256) void k_bcount(
    const int* __restrict__ ei, int E, int Et, int nbk, int* __restrict__ bcnt)
{
    __shared__ int h[512];
    for (int i = threadIdx.x; i < nbk; i += 256) h[i] = 0;
    __syncthreads();
    const int start = blockIdx.x * 4096;
    const int end   = min(start + 4096, Et);
    for (int i = start + threadIdx.x; i < end; i += 256) {
        int d = (i < E) ? ei[E + i] : i - E;
        atomicAdd(&h[d >> BSH], 1);
    }
    __syncthreads();
    for (int i = threadIdx.x; i < nbk; i += 256)
        if (h[i]) atomicAdd(&bcnt[i], h[i]);
}

// + folded graph-boundary search (was k_bounds)
__global__ __launch_bounds__(512) void k_bscan(
    const int* __restrict__ bcnt, int nbk, int Et,
    int* __restrict__ bbase, int* __restrict__ bcur,
    const int* __restrict__ batch, int* __restrict__ gbound, int N, int G)
{
    __shared__ int s[512];
    int v = (threadIdx.x < nbk) ? bcnt[threadIdx.x] : 0;
    s[threadIdx.x] = v;
    __syncthreads();
#pragma unroll
    for (int off = 1; off < 512; off <<= 1) {
        int t = (threadIdx.x >= off) ? s[threadIdx.x - off] : 0;
        __syncthreads();
        s[threadIdx.x] += t;
        __syncthreads();
    }
    if (threadIdx.x < nbk) {
        int ex = s[threadIdx.x] - v;
        bbase[threadIdx.x] = ex;
        bcur[threadIdx.x]  = ex;
    }
    if (threadIdx.x == 0) bbase[nbk] = Et;
    if (threadIdx.x <= (unsigned)G) {
        int target = threadIdx.x;
        int lo = 0, hi = N;
        while (lo < hi) { int mid = (lo + hi) >> 1; if (batch[mid] < target) lo = mid + 1; else hi = mid; }
        gbound[threadIdx.x] = lo;
    }
}

// ebuk entry: (d & 127) << 25 | src   (src < 2^25)
__global__ __launch_bounds__(256) void k_bscatter(
    const int* __restrict__ ei, int E, int Et, int nbk,
    int* __restrict__ bcur, unsigned* __restrict__ ebuk)
{
    __shared__ int h[512];
    __shared__ int cur[512];
    for (int i = threadIdx.x; i < nbk; i += 256) h[i] = 0;
    __syncthreads();
    const int start = blockIdx.x * 4096;
    const int end   = min(start + 4096, Et);
    for (int i = start + threadIdx.x; i < end; i += 256) {
        int d = (i < E) ? ei[E + i] : i - E;
        atomicAdd(&h[d >> BSH], 1);
    }
    __syncthreads();
    for (int i = threadIdx.x; i < nbk; i += 256)
        cur[i] = h[i] ? atomicAdd(&bcur[i], h[i]) : 0;
    __syncthreads();
    for (int i = start + threadIdx.x; i < end; i += 256) {
        int s, d;
        if (i < E) { s = ei[i]; d = ei[E + i]; } else { s = i - E; d = s; }
        int p = atomicAdd(&cur[d >> BSH], 1);
        ebuk[p] = ((unsigned)(d & (BW - 1)) << 25) | (unsigned)s;
    }
}

// ===== Fused: per-bucket deg + local scan -> rowp, then place edges -> esrc =====
__global__ __launch_bounds__(256) void k_csr(
    const unsigned* __restrict__ ebuk, const int* __restrict__ bbase,
    int N, int Et, int* __restrict__ rowp, int* __restrict__ esrc)
{
    const int b = blockIdx.x;
    __shared__ int cnt[BW];
    __shared__ int pre[BW];
    __shared__ int lcur[BW];
    if (threadIdx.x < BW) cnt[threadIdx.x] = 0;
    __syncthreads();
    const int e0 = bbase[b], e1 = bbase[b + 1];
    for (int i = e0 + threadIdx.x; i < e1; i += 256)
        atomicAdd(&cnt[ebuk[i] >> 25], 1);
    __syncthreads();
    if (threadIdx.x < BW) pre[threadIdx.x] = cnt[threadIdx.x];
    __syncthreads();
#pragma unroll
    for (int off = 1; off < BW; off <<= 1) {
        int v = (threadIdx.x < BW && threadIdx.x >= off) ? pre[threadIdx.x - off] : 0;
        __syncthreads();
        if (threadIdx.x < BW) pre[threadIdx.x] += v;
        __syncthreads();
    }
    const int d0 = b << BSH;
    if (threadIdx.x < BW) {
        int r = e0 + pre[threadIdx.x] - cnt[threadIdx.x];   // exclusive
        int d = d0 + threadIdx.x;
        if (d < N) rowp[d] = r;
        lcur[threadIdx.x] = r;
    }
    if (b == 0 && threadIdx.x == 0) rowp[N] = Et;
    __syncthreads();
    for (int i = e0 + threadIdx.x; i < e1; i += 256) {
        unsigned e = ebuk[i];
        int p = atomicAdd(&lcur[e >> 25], 1);
        esrc[p] = (int)(e & 0x1FFFFFFu);
    }
}

// ---------------- GEMM1: h1(bf16) = x @ W1 (128->128), 4x4 blocking ----------------
__global__ __launch_bounds__(256) void k_gemm1(
    const float* __restrict__ x, const float* __restrict__ W,
    const float* __restrict__ att_s, const float* __restrict__ att_d,
    ushort* __restrict__ h1, float* __restrict__ asT, float* __restrict__ ad1,
    unsigned* __restrict__ gmaxu, int N)
{
    __shared__ __align__(16) float sW[16][128];   // 8 KB
    __shared__ __align__(16) float sX[32][16];    // 2 KB
    __shared__ unsigned smax[4];
    const int t  = threadIdx.x;
    const int c4 = t & 31;             // col group (cols c4*4 .. c4*4+3)
    const int rg = t >> 5;             // row group (rows rg*4 .. rg*4+3)
    const int row0 = blockIdx.x * 32;
    const float4* W4 = (const float4*)W;   // W row = 32 float4

    if (t < 4) smax[t] = 0;            // first loop barrier makes this visible

    float4 acc[4];
#pragma unroll
    for (int i = 0; i < 4; i++) acc[i] = {0.f, 0.f, 0.f, 0.f};

    for (int k0 = 0; k0 < 128; k0 += 16) {
        __syncthreads();
#pragma unroll
        for (int j = 0; j < 2; j++) {
            int idx = j * 256 + t;                 // 0..511
            int r = idx >> 5, cc = idx & 31;
            *(float4*)&sW[r][cc * 4] = W4[(k0 + r) * 32 + cc];
        }
        if (t < 128) {
            int r = t >> 2, q = t & 3;
            int row = row0 + r;
            float4 v = {0.f, 0.f, 0.f, 0.f};
            if (row < N) v = *(const float4*)&x[(long long)row * 128 + k0 + q * 4];
            *(float4*)&sX[r][q * 4] = v;
        }
        __syncthreads();
#pragma unroll
        for (int g = 0; g < 4; g++) {
            const int kk = g * 4;
            const float4 w0 = *(const float4*)&sW[kk + 0][c4 * 4];
            const float4 w1 = *(const float4*)&sW[kk + 1][c4 * 4];
            const float4 w2 = *(const float4*)&sW[kk + 2][c4 * 4];
            const float4 w3 = *(const float4*)&sW[kk + 3][c4 * 4];
#pragma unroll
            for (int i = 0; i < 4; i++) {
                const float4 xv = *(const float4*)&sX[rg * 4 + i][kk];  // broadcast
                acc[i].x = fmaf(xv.x, w0.x, acc[i].x);
                acc[i].y = fmaf(xv.x, w0.y, acc[i].y);
                acc[i].z = fmaf(xv.x, w0.z, acc[i].z);
                acc[i].w = fmaf(xv.x, w0.w, acc[i].w);
                acc[i].x = fmaf(xv.y, w1.x, acc[i].x);
                acc[i].y = fmaf(xv.y, w1.y, acc[i].y);
                acc[i].z = fmaf(xv.y, w1.z, acc[i].z);
                acc[i].w = fmaf(xv.y, w1.w, acc[i].w);
                acc[i].x = fmaf(xv.z, w2.x, acc[i].x);
                acc[i].y = fmaf(xv.z, w2.y, acc[i].y);
                acc[i].z = fmaf(xv.z, w2.z, acc[i].z);
                acc[i].w = fmaf(xv.z, w2.w, acc[i].w);
                acc[i].x = fmaf(xv.w, w3.x, acc[i].x);
                acc[i].y = fmaf(xv.w, w3.y, acc[i].y);
                acc[i].z = fmaf(xv.w, w3.z, acc[i].z);
                acc[i].w = fmaf(xv.w, w3.w, acc[i].w);
            }
        }
    }

    const float4 avs = *(const float4*)&att_s[c4 * 4];
    const float4 avd = *(const float4*)&att_d[c4 * 4];
    const int hd = c4 >> 3;                        // head of this thread's 4 cols
    float lmax = -INFINITY;
#pragma unroll
    for (int i = 0; i < 4; i++) {
        int row = row0 + rg * 4 + i;
        if (row < N) {
            ushort4 hb;
            hb.x = f2bf(acc[i].x); hb.y = f2bf(acc[i].y);
            hb.z = f2bf(acc[i].z); hb.w = f2bf(acc[i].w);
            *(ushort4*)&h1[(long long)row * 128 + c4 * 4] = hb;
            float s = acc[i].x * avs.x + acc[i].y * avs.y + acc[i].z * avs.z + acc[i].w * avs.w;
            float d = acc[i].x * avd.x + acc[i].y * avd.y + acc[i].z * avd.z + acc[i].w * avd.w;
#pragma unroll
            for (int off = 4; off > 0; off >>= 1) {    // reduce over 8 col-threads of head
                s += __shfl_xor(s, off, 64);
                d += __shfl_xor(d, off, 64);
            }
            if ((c4 & 7) == 0) {
                asT[(unsigned)hd * (unsigned)N + row] = s;
                ad1[row * 4 + hd] = d;
                lmax = fmaxf(lmax, s);
            }
        }
    }
    if ((c4 & 7) == 0) atomicMax(&smax[hd], fflip(lmax));
    __syncthreads();
    if (t < 4 && smax[t]) atomicMax(&gmaxu[t], smax[t]);
}

// ---------------- GEMM2: h2(bf16) = elu(out1(bf16)+b1) @ W2 (128->32) ----------------
__global__ __launch_bounds__(256) void k_gemm2(
    const ushort* __restrict__ xin, const float* __restrict__ W,
    const float* __restrict__ b1,
    const float* __restrict__ att_s, const float* __restrict__ att_d,
    ushort* __restrict__ h2, float* __restrict__ as2, float* __restrict__ ad2,
    unsigned* __restrict__ gmax2u, int N)
{
    __shared__ __align__(16) float sW[16][32];    // 2 KB
    __shared__ __align__(16) float sX[128][16];   // 8 KB
    __shared__ unsigned smax1;
    const int t  = threadIdx.x;
    const int c4 = t & 7;              // col group (cols c4*4 .. c4*4+3)
    const int rg = t >> 3;             // row group (rows rg*4 .. rg*4+3)
    const int row0 = blockIdx.x * 128;
    const float4* W4 = (const float4*)W;          // W row = 8 float4

    if (t == 0) smax1 = 0;

    float4 acc[4];
#pragma unroll
    for (int i = 0; i < 4; i++) acc[i] = {0.f, 0.f, 0.f, 0.f};

    for (int k0 = 0; k0 < 128; k0 += 16) {
        __syncthreads();
        if (t < 128) {                 // stage W tile: 16x32 = 128 float4
            int r = t >> 3, cc = t & 7;
            *(float4*)&sW[r][cc * 4] = W4[(k0 + r) * 8 + cc];
        }
#pragma unroll
        for (int j = 0; j < 2; j++) {  // stage X tile: 128x16 = 512 ushort4-loads
            int idx = j * 256 + t;
            int r = idx >> 2, q = idx & 3;
            int row = row0 + r;
            float4 v = {0.f, 0.f, 0.f, 0.f};
            if (row < N) {
                const ushort4 uv = *(const ushort4*)&xin[(long long)row * 128 + k0 + q * 4];
                float4 b = *(const float4*)&b1[k0 + q * 4];
                v.x = elu1f(bf2f(uv.x) + b.x); v.y = elu1f(bf2f(uv.y) + b.y);
                v.z = elu1f(bf2f(uv.z) + b.z); v.w = elu1f(bf2f(uv.w) + b.w);
            }
            *(float4*)&sX[r][q * 4] = v;
        }
        __syncthreads();
#pragma unroll
        for (int g = 0; g < 4; g++) {
            const int kk = g * 4;
            const float4 w0 = *(const float4*)&sW[kk + 0][c4 * 4];
            const float4 w1 = *(const float4*)&sW[kk + 1][c4 * 4];
            const float4 w2 = *(const float4*)&sW[kk + 2][c4 * 4];
            const float4 w3 = *(const float4*)&sW[kk + 3][c4 * 4];
#pragma unroll
            for (int i = 0; i < 4; i++) {
                const float4 xv = *(const float4*)&sX[rg * 4 + i][kk];
                acc[i].x = fmaf(xv.x, w0.x, acc[i].x);
                acc[i].y = fmaf(xv.x, w0.y, acc[i].y);
                acc[i].z = fmaf(xv.x, w0.z, acc[i].z);
                acc[i].w = fmaf(xv.x, w0.w, acc[i].w);
                acc[i].x = fmaf(xv.y, w1.x, acc[i].x);
                acc[i].y = fmaf(xv.y, w1.y, acc[i].y);
                acc[i].z = fmaf(xv.y, w1.z, acc[i].z);
                acc[i].w = fmaf(xv.y, w1.w, acc[i].w);
                acc[i].x = fmaf(xv.z, w2.x, acc[i].x);
                acc[i].y = fmaf(xv.z, w2.y, acc[i].y);
                acc[i].z = fmaf(xv.z, w2.z, acc[i].z);
                acc[i].w = fmaf(xv.z, w2.w, acc[i].w);
                acc[i].x = fmaf(xv.w, w3.x, acc[i].x);
                acc[i].y = fmaf(xv.w, w3.y, acc[i].y);
                acc[i].z = fmaf(xv.w, w3.z, acc[i].z);
                acc[i].w = fmaf(xv.w, w3.w, acc[i].w);
            }
        }
    }

    const float4 avs = *(const float4*)&att_s[c4 * 4];
    const float4 avd = *(const float4*)&att_d[c4 * 4];
    float lmax = -INFINITY;
#pragma unroll
    for (int i = 0; i < 4; i++) {
        int row = row0 + rg * 4 + i;
        if (row < N) {
            ushort4 hb;
            hb.x = f2bf(acc[i].x); hb.y = f2bf(acc[i].y);
            hb.z = f2bf(acc[i].z); hb.w = f2bf(acc[i].w);
            *(ushort4*)&h2[(long long)row * 32 + c4 * 4] = hb;
            float s = acc[i].x * avs.x + acc[i].y * avs.y + acc[i].z * avs.z + acc[i].w * avs.w;
            float d = acc[i].x * avd.x + acc[i].y * avd.y + acc[i].z * avd.z + acc[i].w * avd.w;
#pragma unroll
            for (int off = 4; off > 0; off >>= 1) {    // reduce over 8 col-threads
                s += __shfl_xor(s, off, 64);
                d += __shfl_xor(d, off, 64);
            }
            if (c4 == 0) {
                as2[row] = s; ad2[row] = d;
                lmax = fmaxf(lmax, s);
            }
        }
    }
    if (c4 == 0) atomicMax(&smax1, fflip(lmax));
    __syncthreads();
    if (t == 0 && smax1) atomicMax(&gmax2u[0], smax1);
}

// ========== Fused GAT aggregation, layer 1 (H=4, C=32): one wave per dst ==========
__global__ __launch_bounds__(256) void k_agg1(
    const int* __restrict__ row, const int* __restrict__ esrc,
    const float* __restrict__ asT, const float* __restrict__ ad,  // [4][N], [N][4]
    const unsigned* __restrict__ gmaxu,                           // [4] flipped
    const ushort* __restrict__ h,                                 // [N][128] bf16
    ushort* __restrict__ out, int N)                              // [N][128] bf16
{
    const int lane = threadIdx.x & 63;
    const int wid  = threadIdx.x >> 6;
    const int n = blockIdx.x * 4 + wid;
    if (n >= N) return;
    const int e0 = row[n], e1 = row[n + 1];

    const float4 ad4 = *(const float4*)&ad[n * 4];
    const int half = lane >> 5;
    const int l    = lane & 31;                 // 4 cols per lane: l*4..l*4+3
    const int hd   = l >> 3;                    // head of those cols
    const float adh = hd == 0 ? ad4.x : hd == 1 ? ad4.y : hd == 2 ? ad4.z : ad4.w;
    float mh = funflip(gmaxu[hd]) + adh;
    mh = mh >= 0.f ? mh : NEG_SLOPE * mh;

    const float* asH = asT + (unsigned)hd * (unsigned)N;
    const unsigned lofs = (unsigned)(l * 4);
    float4 acc = {0.f, 0.f, 0.f, 0.f};
    float wsum = 0.f;
    for (int base = e0; base < e1; base += 8) {
        const int eA = base + half,     eB = base + 2 + half;
        const int eC = base + 4 + half, eD = base + 6 + half;
        const bool vA = eA < e1, vB = eB < e1, vC = eC < e1, vD = eD < e1;
        const int sA = vA ? esrc[eA] : 0;
        const int sB = vB ? esrc[eB] : 0;
        const int sC = vC ? esrc[eC] : 0;
        const int sD = vD ? esrc[eD] : 0;
        const float aA = asH[sA];
        const float aB = asH[sB];
        const float aC = asH[sC];
        const float aD = asH[sD];
        const ushort4 hA = *(const ushort4*)&h[(unsigned)sA * 128u + lofs];
        const ushort4 hB = *(const ushort4*)&h[(unsigned)sB * 128u + lofs];
        const ushort4 hC = *(const ushort4*)&h[(unsigned)sC * 128u + lofs];
        const ushort4 hD = *(const ushort4*)&h[(unsigned)sD * 128u + lofs];

        float evA = aA + adh;
        evA = evA >= 0.f ? evA : NEG_SLOPE * evA;
        const float wA = vA ? __expf(evA - mh) : 0.f;
        float evB = aB + adh;
        evB = evB >= 0.f ? evB : NEG_SLOPE * evB;
        const float wB = vB ? __expf(evB - mh) : 0.f;
        float evC = aC + adh;
        evC = evC >= 0.f ? evC : NEG_SLOPE * evC;
        const float wC = vC ? __expf(evC - mh) : 0.f;
        float evD = aD + adh;
        evD = evD >= 0.f ? evD : NEG_SLOPE * evD;
        const float wD = vD ? __expf(evD - mh) : 0.f;

        acc.x = fmaf(wA, bf2f(hA.x), acc.x);
        acc.y = fmaf(wA, bf2f(hA.y), acc.y);
        acc.z = fmaf(wA, bf2f(hA.z), acc.z);
        acc.w = fmaf(wA, bf2f(hA.w), acc.w);
        acc.x = fmaf(wB, bf2f(hB.x), acc.x);
        acc.y = fmaf(wB, bf2f(hB.y), acc.y);
        acc.z = fmaf(wB, bf2f(hB.z), acc.z);
        acc.w = fmaf(wB, bf2f(hB.w), acc.w);
        acc.x = fmaf(wC, bf2f(hC.x), acc.x);
        acc.y = fmaf(wC, bf2f(hC.y), acc.y);
        acc.z = fmaf(wC, bf2f(hC.z), acc.z);
        acc.w = fmaf(wC, bf2f(hC.w), acc.w);
        acc.x = fmaf(wD, bf2f(hD.x), acc.x);
        acc.y = fmaf(wD, bf2f(hD.y), acc.y);
        acc.z = fmaf(wD, bf2f(hD.z), acc.z);
        acc.w = fmaf(wD, bf2f(hD.w), acc.w);
        wsum += (wA + wB) + (wC + wD);
    }
    acc.x += __shfl_xor(acc.x, 32, 64);
    acc.y += __shfl_xor(acc.y, 32, 64);
    acc.z += __shfl_xor(acc.z, 32, 64);
    acc.w += __shfl_xor(acc.w, 32, 64);
    wsum  += __shfl_xor(wsum, 32, 64);

    if (half == 0) {
        const float inv = 1.f / (wsum + 1e-16f);
        ushort4 ob;
        ob.x = f2bf(acc.x * inv); ob.y = f2bf(acc.y * inv);
        ob.z = f2bf(acc.z * inv); ob.w = f2bf(acc.w * inv);
        *(ushort4*)&out[(long long)n * 128 + l * 4] = ob;
    }
}

// ========== Fused GAT aggregation, layer 2 (H=1, C=32): one wave per dst ==========
__global__ __launch_bounds__(256) void k_agg2(
    const int* __restrict__ row, const int* __restrict__ esrc,
    const float* __restrict__ as, const float* __restrict__ ad,   // [N]
    const unsigned* __restrict__ gmax2u,                          // [1] flipped
    const ushort* __restrict__ h,                                 // [N][32] bf16
    float* __restrict__ out, int N)                               // [N][32]
{
    const int lane = threadIdx.x & 63;
    const int wid  = threadIdx.x >> 6;
    const int n = blockIdx.x * 4 + wid;
    if (n >= N) return;
    const int e0 = row[n], e1 = row[n + 1];
    const float adv = ad[n];
    float m = funflip(gmax2u[0]) + adv;
    m = m >= 0.f ? m : NEG_SLOPE * m;

    const int g  = lane >> 3;                    // edge slot 0..7
    const int l8 = lane & 7;                     // 4 cols: l8*4..l8*4+3
    const unsigned lofs = (unsigned)(l8 * 4);
    float4 acc = {0.f, 0.f, 0.f, 0.f};
    float wsum = 0.f;
    for (int base = e0; base < e1; base += 32) {
        const int eA = base + g,      eB = base + 8 + g;
        const int eC = base + 16 + g, eD = base + 24 + g;
        const bool vA = eA < e1, vB = eB < e1, vC = eC < e1, vD = eD < e1;
        const int sA = vA ? esrc[eA] : 0;
        const int sB = vB ? esrc[eB] : 0;
        const int sC = vC ? esrc[eC] : 0;
        const int sD = vD ? esrc[eD] : 0;
        const float asA = as[sA], asB = as[sB], asC = as[sC], asD = as[sD];
        const ushort4 hA = *(const ushort4*)&h[(unsigned)sA * 32u + lofs];
        const ushort4 hB = *(const ushort4*)&h[(unsigned)sB * 32u + lofs];
        const ushort4 hC = *(const ushort4*)&h[(unsigned)sC * 32u + lofs];
        const ushort4 hD = *(const ushort4*)&h[(unsigned)sD * 32u + lofs];

        float evA = asA + adv; evA = evA >= 0.f ? evA : NEG_SLOPE * evA;
        const float wA = vA ? __expf(evA - m) : 0.f;
        float evB = asB + adv; evB = evB >= 0.f ? evB : NEG_SLOPE * evB;
        const float wB = vB ? __expf(evB - m) : 0.f;
        float evC = asC + adv; evC = evC >= 0.f ? evC : NEG_SLOPE * evC;
        const float wC = vC ? __expf(evC - m) : 0.f;
        float evD = asD + adv; evD = evD >= 0.f ? evD : NEG_SLOPE * evD;
        const float wD = vD ? __expf(evD - m) : 0.f;

        acc.x = fmaf(wA, bf2f(hA.x), acc.x);
        acc.y = fmaf(wA, bf2f(hA.y), acc.y);
        acc.z = fmaf(wA, bf2f(hA.z), acc.z);
        acc.w = fmaf(wA, bf2f(hA.w), acc.w);
        acc.x = fmaf(wB, bf2f(hB.x), acc.x);
        acc.y = fmaf(wB, bf2f(hB.y), acc.y);
        acc.z = fmaf(wB, bf2f(hB.z), acc.z);
        acc.w = fmaf(wB, bf2f(hB.w), acc.w);
        acc.x = fmaf(wC, bf2f(hC.x), acc.x);
        acc.y = fmaf(wC, bf2f(hC.y), acc.y);
        acc.z = fmaf(wC, bf2f(hC.z), acc.z);
        acc.w = fmaf(wC, bf2f(hC.w), acc.w);
        acc.x = fmaf(wD, bf2f(hD.x), acc.x);
        acc.y = fmaf(wD, bf2f(hD.y), acc.y);
        acc.z = fmaf(wD, bf2f(hD.z), acc.z);
        acc.w = fmaf(wD, bf2f(hD.w), acc.w);
        wsum += (wA + wB) + (wC + wD);
    }
#pragma unroll
    for (int off = 8; off < 64; off <<= 1) {
        acc.x += __shfl_xor(acc.x, off, 64);
        acc.y += __shfl_xor(acc.y, off, 64);
        acc.z += __shfl_xor(acc.z, off, 64);
        acc.w += __shfl_xor(acc.w, off, 64);
        wsum  += __shfl_xor(wsum, off, 64);
    }
    if (lane < 8) {
        const float inv = 1.f / (wsum + 1e-16f);
        float4 o; o.x = acc.x * inv; o.y = acc.y * inv; o.z = acc.z * inv; o.w = acc.w * inv;
        *(float4*)&out[(long long)n * 32 + lane * 4] = o;
    }
}

// ========== Gate MLP: full-grid parallel, one 32-lane group per node ==========
__global__ __launch_bounds__(256) void k_gate(
    const float* __restrict__ out2, const float* __restrict__ b2,
    const float* __restrict__ gw1, const float* __restrict__ gb1,
    const float* __restrict__ gw2, const float* __restrict__ gb2,
    float* __restrict__ gate, int N)
{
    const int c = threadIdx.x & 31, grp = threadIdx.x >> 5;
    const int n = blockIdx.x * 8 + grp;
    if (n >= N) return;
    float v = out2[(long long)n * 32 + c] + b2[c];
    v = elu1f(v);
    float t1 = gb1[c];
#pragma unroll
    for (int k = 0; k < 32; k++) {
        float hk = __shfl(v, k, 32);
        t1 = fmaf(hk, gw1[k * 32 + c], t1);
    }
    t1 = fmaxf(t1, 0.f);
    float gv = t1 * gw2[c];
#pragma unroll
    for (int off = 16; off > 0; off >>= 1) gv += __shfl_xor(gv, off, 32);
    if (c == 0) gate[n] = gv + gb2[0];
}

// ========== Pool stage 1: per-chunk max -> atomicMax per block (8 chunks/graph) =====
__global__ __launch_bounds__(256) void k_gmax(
    const float* __restrict__ gate, const int* __restrict__ gbound,
    unsigned* __restrict__ gmax)
{
    const int g  = blockIdx.x >> 3;
    const int ch = blockIdx.x & 7;
    const int s0 = gbound[g], s1 = gbound[g + 1];
    const int len = s1 - s0;
    const int c0 = s0 + (int)(((long long)len * ch) >> 3);
    const int c1 = s0 + (int)(((long long)len * (ch + 1)) >> 3);

    __shared__ float sred[4];
    float m = -INFINITY;
    for (int n = c0 + threadIdx.x; n < c1; n += 256) m = fmaxf(m, gate[n]);
#pragma unroll
    for (int off = 32; off > 0; off >>= 1) m = fmaxf(m, __shfl_xor(m, off, 64));
    if ((threadIdx.x & 63) == 0) sred[threadIdx.x >> 6] = m;
    __syncthreads();
    if (threadIdx.x == 0) {
        m = fmaxf(fmaxf(sred[0], sred[1]), fmaxf(sred[2], sred[3]));
        atomicMax(&gmax[g], fflip(m));
    }
}

// ========== Pool stage 2: per-chunk partial weighted sums (no atomics) ==========
__global__ __launch_bounds__(256) void k_pool3(
    const float* __restrict__ out2, const float* __restrict__ b2,
    const float* __restrict__ gate, const int* __restrict__ gbound,
    const unsigned* __restrict__ gmax, float* __restrict__ partials)
{
    const int g  = blockIdx.x >> 3;
    const int ch = blockIdx.x & 7;
    const int s0 = gbound[g], s1 = gbound[g + 1];
    const int len = s1 - s0;
    const int c0 = s0 + (int)(((long long)len * ch) >> 3);
    const int c1 = s0 + (int)(((long long)len * (ch + 1)) >> 3);

    const int c   = threadIdx.x & 31;
    const int grp = threadIdx.x >> 5;
    const float gm = funflip(gmax[g]);
    const float bc = b2[c];

    __shared__ float sacc[8][32];
    __shared__ float swsum[8];

    float acc = 0.f, wsum = 0.f;
    for (int n = c0 + grp; n < c1; n += 8) {
        float v = elu1f(out2[(long long)n * 32 + c] + bc);
        float ge = __expf(gate[n] - gm);
        acc = fmaf(ge, v, acc);
        wsum += ge;
    }
    sacc[grp][c] = acc;
    if (c == 0) swsum[grp] = wsum;
    __syncthreads();

    if (grp == 0) {
        float a = 0.f, wtot = 0.f;
#pragma unroll
        for (int i = 0; i < 8; i++) { a += sacc[i][c]; wtot += swsum[i]; }
        partials[(long long)blockIdx.x * 33 + c] = a;
        if (c == 0) partials[(long long)blockIdx.x * 33 + 32] = wtot;
    }
}

// ========== Pool stage 3: reduce 8 partials per graph, divide, write out ==========
__global__ __launch_bounds__(256) void k_pool4(
    const float* __restrict__ partials, float* __restrict__ out)
{
    const int g   = blockIdx.x;
    const int c   = threadIdx.x & 31;
    const int p   = threadIdx.x >> 5;

    __shared__ float sacc[8][32];
    __shared__ float swsum[8];

    sacc[p][c] = partials[(long long)(g * 8 + p) * 33 + c];
    if (c == 0) swsum[p] = partials[(long long)(g * 8 + p) * 33 + 32];
    __syncthreads();

    if (p == 0) {
        float a = 0.f, wtot = 0.f;
#pragma unroll
        for (int i = 0; i < 8; i++) { a += sacc[i][c]; wtot += swsum[i]; }
        out[g * 32 + c] = a / (wtot + 1e-16f);
    }
}

extern "C" void kernel_launch(void* const* d_in, const int* in_sizes, int n_in,
                              void* d_out, int out_size, void* d_ws, size_t ws_size,
                              hipStream_t stream)
{
    const float* x    = (const float*)d_in[0];
    const int*   ei   = (const int*)d_in[1];
    const int*   batch= (const int*)d_in[2];
    const float* W1   = (const float*)d_in[3];
    const float* as1w = (const float*)d_in[4];
    const float* ad1w = (const float*)d_in[5];
    const float* b1   = (const float*)d_in[6];
    const float* W2   = (const float*)d_in[7];
    const float* as2w = (const float*)d_in[8];
    const float* ad2w = (const float*)d_in[9];
    const float* b2   = (const float*)d_in[10];
    const float* gw1  = (const float*)d_in[11];
    const float* gb1  = (const float*)d_in[12];
    const float* gw2  = (const float*)d_in[13];
    const float* gb2  = (const float*)d_in[14];

    const int N  = in_sizes[2];
    const int E  = in_sizes[1] / 2;
    const int Et = E + N;
    const int G  = 64;
    const int nbk   = (N + BW - 1) >> BSH;   // 391 buckets (<=512)
    const int nchk  = (Et + 4095) / 4096;    // bucket-build chunks
    const int nblk1 = (N + 31) / 32;         // gemm1 blocks
    const int nblk2 = (N + 127) / 128;       // gemm2 blocks

    float* ws = (float*)d_ws;
    size_t o = 0;
    unsigned* ebuk = (unsigned*)(ws + o); o += (size_t)Et * 2;  // u32 used; +Et pad keeps h1 at the round-14 offset (measured lower FETCH)
    ushort* h1 = (ushort*)(ws + o); o += (size_t)N * 64;   // bf16 [N][128]
    ushort* out1 = (ushort*)(ws + o); o += (size_t)N * 64; // bf16 [N][128]
    ushort* h2 = (ushort*)(ws + o); o += (size_t)N * 16;   // bf16 [N][32]
    float* out2 = ws + o; o += (size_t)N * 32;
    float* asT1 = ws + o; o += (size_t)N * 4;              // [4][N] transposed
    float* a_d1 = ws + o; o += (size_t)N * 4;
    float* a_s2 = ws + o; o += (size_t)N;
    float* a_d2 = ws + o; o += (size_t)N;
    float* gate = ws + o; o += (size_t)N;
    int*   rowp = (int*)(ws + o); o += (size_t)N + 1;
    int*   esrc = (int*)(ws + o); o += (size_t)Et;
    int*   bbase= (int*)(ws + o); o += (size_t)nbk + 1;
    int*   bcur = (int*)(ws + o); o += (size_t)nbk;        // init by k_bscan
    int*   gbound = (int*)(ws + o); o += G + 1;
    float* partials = ws + o; o += (size_t)G * 8 * 33;
    // ---- zeroed region (one memset): bcnt + gmax + gmaxu + gmax2u ----
    size_t zstart = o;
    int*      bcnt   = (int*)(ws + o); o += (size_t)nbk;
    unsigned* gmax   = (unsigned*)(ws + o); o += G;
    unsigned* gmaxu  = (unsigned*)(ws + o); o += 4;        // layer-1 head maxes (flipped)
    unsigned* gmax2u = (unsigned*)(ws + o); o += 4;        // layer-2 max (flipped)
    size_t zbytes = (o - zstart) * sizeof(float);

    hipMemsetAsync(ws + zstart, 0, zbytes, stream);

    // ---- bucketed CSR build (shared by both layers) + graph bounds ----
    k_bcount  <<<nchk, 256, 0, stream>>>(ei, E, Et, nbk, bcnt);
    k_bscan   <<<1, 512, 0, stream>>>(bcnt, nbk, Et, bbase, bcur, batch, gbound, N, G);
    k_bscatter<<<nchk, 256, 0, stream>>>(ei, E, Et, nbk, bcur, ebuk);
    k_csr     <<<nbk, 256, 0, stream>>>(ebuk, bbase, N, Et, rowp, esrc);

    // ---- GAT layer 1 ----
    k_gemm1<<<nblk1, 256, 0, stream>>>(x, W1, as1w, ad1w, h1, asT1, a_d1, gmaxu, N);
    k_agg1 <<<(N + 3) / 4, 256, 0, stream>>>(rowp, esrc, asT1, a_d1, gmaxu, h1, out1, N);

    // ---- GAT layer 2 (elu(out1+b1) fused into gemm2 load) ----
    k_gemm2<<<nblk2, 256, 0, stream>>>(out1, W2, b1, as2w, ad2w, h2, a_s2, a_d2, gmax2u, N);
    k_agg2 <<<(N + 3) / 4, 256, 0, stream>>>(rowp, esrc, a_s2, a_d2, gmax2u, h2, out2, N);

    // ---- attentional pooling: gate, chunked max, partial sums, final reduce ----
    k_gate <<<(N + 7) / 8, 256, 0, stream>>>(out2, b2, gw1, gb1, gw2, gb2, gate, N);
    k_gmax <<<G * 8, 256, 0, stream>>>(gate, gbound, gmax);
    k_pool3<<<G * 8, 256, 0, stream>>>(out2, b2, gate, gbound, gmax, partials);
    k_pool4<<<G, 256, 0, stream>>>(partials, (float*)d_out);
}

// Round 21
// 203.432 us; speedup vs baseline: 1.5720x; 1.0076x over previous
//
#include <hip/hip_runtime.h>
#include <hip/hip_bf16.h>

#define NEG_SLOPE 0.2f
#define BW  128              // bucket width in dst nodes
#define BSH 7

__device__ __forceinline__ float elu1f(float v) {
    return v > 0.f ? v : expm1f(v);
}
__device__ __forceinline__ float bf2f(ushort u) {
    return __uint_as_float(((unsigned)u) << 16);
}
__device__ __forceinline__ ushort f2bf(float f) {
    return __bfloat16_as_ushort(__float2bfloat16(f));
}
__device__ __forceinline__ unsigned fflip(float f) {
    unsigned u = __float_as_uint(f);
    return (u & 0x80000000u) ? ~u : (u | 0x80000000u);
}
__device__ __forceinline__ float funflip(unsigned u) {
    u = (u & 0x80000000u) ? (u & 0x7FFFFFFFu) : ~u;
    return __uint_as_float(u);
}

// ================= Bucketed CSR build (by dst) =================
__global__ __launch_bounds__(256) void k_bcount(
    const int* __restrict__ ei, int E, int Et, int nbk, int* __restrict__ bcnt)
{
    __shared__ int h[512];
    for (int i = threadIdx.x; i < nbk; i += 256) h[i] = 0;
    __syncthreads();
    const int start = blockIdx.x * 4096;
    const int end   = min(start + 4096, Et);
    for (int i = start + threadIdx.x; i < end; i += 256) {
        int d = (i < E) ? ei[E + i] : i - E;
        atomicAdd(&h[d >> BSH], 1);
    }
    __syncthreads();
    for (int i = threadIdx.x; i < nbk; i += 256)
        if (h[i]) atomicAdd(&bcnt[i], h[i]);
}

// + folded graph-boundary search (was k_bounds)
__global__ __launch_bounds__(512) void k_bscan(
    const int* __restrict__ bcnt, int nbk, int Et,
    int* __restrict__ bbase, int* __restrict__ bcur,
    const int* __restrict__ batch, int* __restrict__ gbound, int N, int G)
{
    __shared__ int s[512];
    int v = (threadIdx.x < nbk) ? bcnt[threadIdx.x] : 0;
    s[threadIdx.x] = v;
    __syncthreads();
#pragma unroll
    for (int off = 1; off < 512; off <<= 1) {
        int t = (threadIdx.x >= off) ? s[threadIdx.x - off] : 0;
        __syncthreads();
        s[threadIdx.x] += t;
        __syncthreads();
    }
    if (threadIdx.x < nbk) {
        int ex = s[threadIdx.x] - v;
        bbase[threadIdx.x] = ex;
        bcur[threadIdx.x]  = ex;
    }
    if (threadIdx.x == 0) bbase[nbk] = Et;
    if (threadIdx.x <= (unsigned)G) {
        int target = threadIdx.x;
        int lo = 0, hi = N;
        while (lo < hi) { int mid = (lo + hi) >> 1; if (batch[mid] < target) lo = mid + 1; else hi = mid; }
        gbound[threadIdx.x] = lo;
    }
}

// ebuk entry: (d & 127) << 25 | src   (src < 2^25)
__global__ __launch_bounds__(256) void k_bscatter(
    const int* __restrict__ ei, int E, int Et, int nbk,
    int* __restrict__ bcur, unsigned* __restrict__ ebuk)
{
    __shared__ int h[512];
    __shared__ int cur[512];
    for (int i = threadIdx.x; i < nbk; i += 256) h[i] = 0;
    __syncthreads();
    const int start = blockIdx.x * 4096;
    const int end   = min(start + 4096, Et);
    for (int i = start + threadIdx.x; i < end; i += 256) {
        int d = (i < E) ? ei[E + i] : i - E;
        atomicAdd(&h[d >> BSH], 1);
    }
    __syncthreads();
    for (int i = threadIdx.x; i < nbk; i += 256)
        cur[i] = h[i] ? atomicAdd(&bcur[i], h[i]) : 0;
    __syncthreads();
    for (int i = start + threadIdx.x; i < end; i += 256) {
        int s, d;
        if (i < E) { s = ei[i]; d = ei[E + i]; } else { s = i - E; d = s; }
        int p = atomicAdd(&cur[d >> BSH], 1);
        ebuk[p] = ((unsigned)(d & (BW - 1)) << 25) | (unsigned)s;
    }
}

// ===== Fused: per-bucket deg + local scan -> rowp, then place edges -> esrc =====
__global__ __launch_bounds__(256) void k_csr(
    const unsigned* __restrict__ ebuk, const int* __restrict__ bbase,
    int N, int Et, int* __restrict__ rowp, int* __restrict__ esrc)
{
    const int b = blockIdx.x;
    __shared__ int cnt[BW];
    __shared__ int pre[BW];
    __shared__ int lcur[BW];
    if (threadIdx.x < BW) cnt[threadIdx.x] = 0;
    __syncthreads();
    const int e0 = bbase[b], e1 = bbase[b + 1];
    for (int i = e0 + threadIdx.x; i < e1; i += 256)
        atomicAdd(&cnt[ebuk[i] >> 25], 1);
    __syncthreads();
    if (threadIdx.x < BW) pre[threadIdx.x] = cnt[threadIdx.x];
    __syncthreads();
#pragma unroll
    for (int off = 1; off < BW; off <<= 1) {
        int v = (threadIdx.x < BW && threadIdx.x >= off) ? pre[threadIdx.x - off] : 0;
        __syncthreads();
        if (threadIdx.x < BW) pre[threadIdx.x] += v;
        __syncthreads();
    }
    const int d0 = b << BSH;
    if (threadIdx.x < BW) {
        int r = e0 + pre[threadIdx.x] - cnt[threadIdx.x];   // exclusive
        int d = d0 + threadIdx.x;
        if (d < N) rowp[d] = r;
        lcur[threadIdx.x] = r;
    }
    if (b == 0 && threadIdx.x == 0) rowp[N] = Et;
    __syncthreads();
    for (int i = e0 + threadIdx.x; i < e1; i += 256) {
        unsigned e = ebuk[i];
        int p = atomicAdd(&lcur[e >> 25], 1);
        esrc[p] = (int)(e & 0x1FFFFFFu);
    }
}

// ---------------- GEMM1: h1(bf16) = x @ W1 (128->128), 4x4 blocking ----------------
__global__ __launch_bounds__(256) void k_gemm1(
    const float* __restrict__ x, const float* __restrict__ W,
    const float* __restrict__ att_s, const float* __restrict__ att_d,
    ushort* __restrict__ h1, float* __restrict__ asT, float* __restrict__ ad1,
    unsigned* __restrict__ gmaxu, int N)
{
    __shared__ __align__(16) float sW[16][128];   // 8 KB
    __shared__ __align__(16) float sX[32][16];    // 2 KB
    __shared__ unsigned smax[4];
    const int t  = threadIdx.x;
    const int c4 = t & 31;             // col group (cols c4*4 .. c4*4+3)
    const int rg = t >> 5;             // row group (rows rg*4 .. rg*4+3)
    const int row0 = blockIdx.x * 32;
    const float4* W4 = (const float4*)W;   // W row = 32 float4

    if (t < 4) smax[t] = 0;            // first loop barrier makes this visible

    float4 acc[4];
#pragma unroll
    for (int i = 0; i < 4; i++) acc[i] = {0.f, 0.f, 0.f, 0.f};

    for (int k0 = 0; k0 < 128; k0 += 16) {
        __syncthreads();
#pragma unroll
        for (int j = 0; j < 2; j++) {
            int idx = j * 256 + t;                 // 0..511
            int r = idx >> 5, cc = idx & 31;
            *(float4*)&sW[r][cc * 4] = W4[(k0 + r) * 32 + cc];
        }
        if (t < 128) {
            int r = t >> 2, q = t & 3;
            int row = row0 + r;
            float4 v = {0.f, 0.f, 0.f, 0.f};
            if (row < N) v = *(const float4*)&x[(long long)row * 128 + k0 + q * 4];
            *(float4*)&sX[r][q * 4] = v;
        }
        __syncthreads();
#pragma unroll
        for (int g = 0; g < 4; g++) {
            const int kk = g * 4;
            const float4 w0 = *(const float4*)&sW[kk + 0][c4 * 4];
            const float4 w1 = *(const float4*)&sW[kk + 1][c4 * 4];
            const float4 w2 = *(const float4*)&sW[kk + 2][c4 * 4];
            const float4 w3 = *(const float4*)&sW[kk + 3][c4 * 4];
#pragma unroll
            for (int i = 0; i < 4; i++) {
                const float4 xv = *(const float4*)&sX[rg * 4 + i][kk];  // broadcast
                acc[i].x = fmaf(xv.x, w0.x, acc[i].x);
                acc[i].y = fmaf(xv.x, w0.y, acc[i].y);
                acc[i].z = fmaf(xv.x, w0.z, acc[i].z);
                acc[i].w = fmaf(xv.x, w0.w, acc[i].w);
                acc[i].x = fmaf(xv.y, w1.x, acc[i].x);
                acc[i].y = fmaf(xv.y, w1.y, acc[i].y);
                acc[i].z = fmaf(xv.y, w1.z, acc[i].z);
                acc[i].w = fmaf(xv.y, w1.w, acc[i].w);
                acc[i].x = fmaf(xv.z, w2.x, acc[i].x);
                acc[i].y = fmaf(xv.z, w2.y, acc[i].y);
                acc[i].z = fmaf(xv.z, w2.z, acc[i].z);
                acc[i].w = fmaf(xv.z, w2.w, acc[i].w);
                acc[i].x = fmaf(xv.w, w3.x, acc[i].x);
                acc[i].y = fmaf(xv.w, w3.y, acc[i].y);
                acc[i].z = fmaf(xv.w, w3.z, acc[i].z);
                acc[i].w = fmaf(xv.w, w3.w, acc[i].w);
            }
        }
    }

    const float4 avs = *(const float4*)&att_s[c4 * 4];
    const float4 avd = *(const float4*)&att_d[c4 * 4];
    const int hd = c4 >> 3;                        // head of this thread's 4 cols
    float lmax = -INFINITY;
#pragma unroll
    for (int i = 0; i < 4; i++) {
        int row = row0 + rg * 4 + i;
        if (row < N) {
            ushort4 hb;
            hb.x = f2bf(acc[i].x); hb.y = f2bf(acc[i].y);
            hb.z = f2bf(acc[i].z); hb.w = f2bf(acc[i].w);
            *(ushort4*)&h1[(long long)row * 128 + c4 * 4] = hb;
            float s = acc[i].x * avs.x + acc[i].y * avs.y + acc[i].z * avs.z + acc[i].w * avs.w;
            float d = acc[i].x * avd.x + acc[i].y * avd.y + acc[i].z * avd.z + acc[i].w * avd.w;
#pragma unroll
            for (int off = 4; off > 0; off >>= 1) {    // reduce over 8 col-threads of head
                s += __shfl_xor(s, off, 64);
                d += __shfl_xor(d, off, 64);
            }
            if ((c4 & 7) == 0) {
                asT[(unsigned)hd * (unsigned)N + row] = s;
                ad1[row * 4 + hd] = d;
                lmax = fmaxf(lmax, s);
            }
        }
    }
    if ((c4 & 7) == 0) atomicMax(&smax[hd], fflip(lmax));
    __syncthreads();
    if (t < 4 && smax[t]) atomicMax(&gmaxu[t], smax[t]);
}

// ---------------- GEMM2: h2(bf16) = elu(out1(bf16)+b1) @ W2 (128->32) ----------------
__global__ __launch_bounds__(256) void k_gemm2(
    const ushort* __restrict__ xin, const float* __restrict__ W,
    const float* __restrict__ b1,
    const float* __restrict__ att_s, const float* __restrict__ att_d,
    ushort* __restrict__ h2, float* __restrict__ as2, float* __restrict__ ad2,
    unsigned* __restrict__ gmax2u, int N)
{
    __shared__ __align__(16) float sW[16][32];    // 2 KB
    __shared__ __align__(16) float sX[128][16];   // 8 KB
    __shared__ unsigned smax1;
    const int t  = threadIdx.x;
    const int c4 = t & 7;              // col group (cols c4*4 .. c4*4+3)
    const int rg = t >> 3;             // row group (rows rg*4 .. rg*4+3)
    const int row0 = blockIdx.x * 128;
    const float4* W4 = (const float4*)W;          // W row = 8 float4

    if (t == 0) smax1 = 0;

    float4 acc[4];
#pragma unroll
    for (int i = 0; i < 4; i++) acc[i] = {0.f, 0.f, 0.f, 0.f};

    for (int k0 = 0; k0 < 128; k0 += 16) {
        __syncthreads();
        if (t < 128) {                 // stage W tile: 16x32 = 128 float4
            int r = t >> 3, cc = t & 7;
            *(float4*)&sW[r][cc * 4] = W4[(k0 + r) * 8 + cc];
        }
#pragma unroll
        for (int j = 0; j < 2; j++) {  // stage X tile: 128x16 = 512 ushort4-loads
            int idx = j * 256 + t;
            int r = idx >> 2, q = idx & 3;
            int row = row0 + r;
            float4 v = {0.f, 0.f, 0.f, 0.f};
            if (row < N) {
                const ushort4 uv = *(const ushort4*)&xin[(long long)row * 128 + k0 + q * 4];
                float4 b = *(const float4*)&b1[k0 + q * 4];
                v.x = elu1f(bf2f(uv.x) + b.x); v.y = elu1f(bf2f(uv.y) + b.y);
                v.z = elu1f(bf2f(uv.z) + b.z); v.w = elu1f(bf2f(uv.w) + b.w);
            }
            *(float4*)&sX[r][q * 4] = v;
        }
        __syncthreads();
#pragma unroll
        for (int g = 0; g < 4; g++) {
            const int kk = g * 4;
            const float4 w0 = *(const float4*)&sW[kk + 0][c4 * 4];
            const float4 w1 = *(const float4*)&sW[kk + 1][c4 * 4];
            const float4 w2 = *(const float4*)&sW[kk + 2][c4 * 4];
            const float4 w3 = *(const float4*)&sW[kk + 3][c4 * 4];
#pragma unroll
            for (int i = 0; i < 4; i++) {
                const float4 xv = *(const float4*)&sX[rg * 4 + i][kk];
                acc[i].x = fmaf(xv.x, w0.x, acc[i].x);
                acc[i].y = fmaf(xv.x, w0.y, acc[i].y);
                acc[i].z = fmaf(xv.x, w0.z, acc[i].z);
                acc[i].w = fmaf(xv.x, w0.w, acc[i].w);
                acc[i].x = fmaf(xv.y, w1.x, acc[i].x);
                acc[i].y = fmaf(xv.y, w1.y, acc[i].y);
                acc[i].z = fmaf(xv.y, w1.z, acc[i].z);
                acc[i].w = fmaf(xv.y, w1.w, acc[i].w);
                acc[i].x = fmaf(xv.z, w2.x, acc[i].x);
                acc[i].y = fmaf(xv.z, w2.y, acc[i].y);
                acc[i].z = fmaf(xv.z, w2.z, acc[i].z);
                acc[i].w = fmaf(xv.z, w2.w, acc[i].w);
                acc[i].x = fmaf(xv.w, w3.x, acc[i].x);
                acc[i].y = fmaf(xv.w, w3.y, acc[i].y);
                acc[i].z = fmaf(xv.w, w3.z, acc[i].z);
                acc[i].w = fmaf(xv.w, w3.w, acc[i].w);
            }
        }
    }

    const float4 avs = *(const float4*)&att_s[c4 * 4];
    const float4 avd = *(const float4*)&att_d[c4 * 4];
    float lmax = -INFINITY;
#pragma unroll
    for (int i = 0; i < 4; i++) {
        int row = row0 + rg * 4 + i;
        if (row < N) {
            ushort4 hb;
            hb.x = f2bf(acc[i].x); hb.y = f2bf(acc[i].y);
            hb.z = f2bf(acc[i].z); hb.w = f2bf(acc[i].w);
            *(ushort4*)&h2[(long long)row * 32 + c4 * 4] = hb;
            float s = acc[i].x * avs.x + acc[i].y * avs.y + acc[i].z * avs.z + acc[i].w * avs.w;
            float d = acc[i].x * avd.x + acc[i].y * avd.y + acc[i].z * avd.z + acc[i].w * avd.w;
#pragma unroll
            for (int off = 4; off > 0; off >>= 1) {    // reduce over 8 col-threads
                s += __shfl_xor(s, off, 64);
                d += __shfl_xor(d, off, 64);
            }
            if (c4 == 0) {
                as2[row] = s; ad2[row] = d;
                lmax = fmaxf(lmax, s);
            }
        }
    }
    if (c4 == 0) atomicMax(&smax1, fflip(lmax));
    __syncthreads();
    if (t == 0 && smax1) atomicMax(&gmax2u[0], smax1);
}

// ========== Fused GAT aggregation, layer 1 (H=4, C=32): one wave per dst ==========
__global__ __launch_bounds__(256) void k_agg1(
    const int* __restrict__ row, const int* __restrict__ esrc,
    const float* __restrict__ asT, const float* __restrict__ ad,  // [4][N], [N][4]
    const unsigned* __restrict__ gmaxu,                           // [4] flipped
    const ushort* __restrict__ h,                                 // [N][128] bf16
    ushort* __restrict__ out, int N)                              // [N][128] bf16
{
    const int lane = threadIdx.x & 63;
    const int wid  = threadIdx.x >> 6;
    const int n = blockIdx.x * 4 + wid;
    if (n >= N) return;
    const int e0 = row[n], e1 = row[n + 1];

    const float4 ad4 = *(const float4*)&ad[n * 4];
    const int half = lane >> 5;
    const int l    = lane & 31;                 // 4 cols per lane: l*4..l*4+3
    const int hd   = l >> 3;                    // head of those cols
    const float adh = hd == 0 ? ad4.x : hd == 1 ? ad4.y : hd == 2 ? ad4.z : ad4.w;
    float mh = funflip(gmaxu[hd]) + adh;
    mh = mh >= 0.f ? mh : NEG_SLOPE * mh;

    const float* asH = asT + (unsigned)hd * (unsigned)N;
    const unsigned lofs = (unsigned)(l * 4);
    float4 acc = {0.f, 0.f, 0.f, 0.f};
    float wsum = 0.f;
    for (int base = e0; base < e1; base += 8) {
        const int eA = base + half,     eB = base + 2 + half;
        const int eC = base + 4 + half, eD = base + 6 + half;
        const bool vA = eA < e1, vB = eB < e1, vC = eC < e1, vD = eD < e1;
        const int sA = vA ? esrc[eA] : 0;
        const int sB = vB ? esrc[eB] : 0;
        const int sC = vC ? esrc[eC] : 0;
        const int sD = vD ? esrc[eD] : 0;
        const float aA = asH[sA];
        const float aB = asH[sB];
        const float aC = asH[sC];
        const float aD = asH[sD];
        const ushort4 hA = *(const ushort4*)&h[(unsigned)sA * 128u + lofs];
        const ushort4 hB = *(const ushort4*)&h[(unsigned)sB * 128u + lofs];
        const ushort4 hC = *(const ushort4*)&h[(unsigned)sC * 128u + lofs];
        const ushort4 hD = *(const ushort4*)&h[(unsigned)sD * 128u + lofs];

        float evA = aA + adh;
        evA = evA >= 0.f ? evA : NEG_SLOPE * evA;
        const float wA = vA ? __expf(evA - mh) : 0.f;
        float evB = aB + adh;
        evB = evB >= 0.f ? evB : NEG_SLOPE * evB;
        const float wB = vB ? __expf(evB - mh) : 0.f;
        float evC = aC + adh;
        evC = evC >= 0.f ? evC : NEG_SLOPE * evC;
        const float wC = vC ? __expf(evC - mh) : 0.f;
        float evD = aD + adh;
        evD = evD >= 0.f ? evD : NEG_SLOPE * evD;
        const float wD = vD ? __expf(evD - mh) : 0.f;

        acc.x = fmaf(wA, bf2f(hA.x), acc.x);
        acc.y = fmaf(wA, bf2f(hA.y), acc.y);
        acc.z = fmaf(wA, bf2f(hA.z), acc.z);
        acc.w = fmaf(wA, bf2f(hA.w), acc.w);
        acc.x = fmaf(wB, bf2f(hB.x), acc.x);
        acc.y = fmaf(wB, bf2f(hB.y), acc.y);
        acc.z = fmaf(wB, bf2f(hB.z), acc.z);
        acc.w = fmaf(wB, bf2f(hB.w), acc.w);
        acc.x = fmaf(wC, bf2f(hC.x), acc.x);
        acc.y = fmaf(wC, bf2f(hC.y), acc.y);
        acc.z = fmaf(wC, bf2f(hC.z), acc.z);
        acc.w = fmaf(wC, bf2f(hC.w), acc.w);
        acc.x = fmaf(wD, bf2f(hD.x), acc.x);
        acc.y = fmaf(wD, bf2f(hD.y), acc.y);
        acc.z = fmaf(wD, bf2f(hD.z), acc.z);
        acc.w = fmaf(wD, bf2f(hD.w), acc.w);
        wsum += (wA + wB) + (wC + wD);
    }
    acc.x += __shfl_xor(acc.x, 32, 64);
    acc.y += __shfl_xor(acc.y, 32, 64);
    acc.z += __shfl_xor(acc.z, 32, 64);
    acc.w += __shfl_xor(acc.w, 32, 64);
    wsum  += __shfl_xor(wsum, 32, 64);

    if (half == 0) {
        const float inv = 1.f / (wsum + 1e-16f);
        ushort4 ob;
        ob.x = f2bf(acc.x * inv); ob.y = f2bf(acc.y * inv);
        ob.z = f2bf(acc.z * inv); ob.w = f2bf(acc.w * inv);
        *(ushort4*)&out[(long long)n * 128 + l * 4] = ob;
    }
}

// ========== Fused GAT aggregation, layer 2 (H=1, C=32): one wave per dst ==========
__global__ __launch_bounds__(256) void k_agg2(
    const int* __restrict__ row, const int* __restrict__ esrc,
    const float* __restrict__ as, const float* __restrict__ ad,   // [N]
    const unsigned* __restrict__ gmax2u,                          // [1] flipped
    const ushort* __restrict__ h,                                 // [N][32] bf16
    float* __restrict__ out, int N)                               // [N][32]
{
    const int lane = threadIdx.x & 63;
    const int wid  = threadIdx.x >> 6;
    const int n = blockIdx.x * 4 + wid;
    if (n >= N) return;
    const int e0 = row[n], e1 = row[n + 1];
    const float adv = ad[n];
    float m = funflip(gmax2u[0]) + adv;
    m = m >= 0.f ? m : NEG_SLOPE * m;

    const int g  = lane >> 3;                    // edge slot 0..7
    const int l8 = lane & 7;                     // 4 cols: l8*4..l8*4+3
    const unsigned lofs = (unsigned)(l8 * 4);
    float4 acc = {0.f, 0.f, 0.f, 0.f};
    float wsum = 0.f;
    for (int base = e0; base < e1; base += 32) {
        const int eA = base + g,      eB = base + 8 + g;
        const int eC = base + 16 + g, eD = base + 24 + g;
        const bool vA = eA < e1, vB = eB < e1, vC = eC < e1, vD = eD < e1;
        const int sA = vA ? esrc[eA] : 0;
        const int sB = vB ? esrc[eB] : 0;
        const int sC = vC ? esrc[eC] : 0;
        const int sD = vD ? esrc[eD] : 0;
        const float asA = as[sA], asB = as[sB], asC = as[sC], asD = as[sD];
        const ushort4 hA = *(const ushort4*)&h[(unsigned)sA * 32u + lofs];
        const ushort4 hB = *(const ushort4*)&h[(unsigned)sB * 32u + lofs];
        const ushort4 hC = *(const ushort4*)&h[(unsigned)sC * 32u + lofs];
        const ushort4 hD = *(const ushort4*)&h[(unsigned)sD * 32u + lofs];

        float evA = asA + adv; evA = evA >= 0.f ? evA : NEG_SLOPE * evA;
        const float wA = vA ? __expf(evA - m) : 0.f;
        float evB = asB + adv; evB = evB >= 0.f ? evB : NEG_SLOPE * evB;
        const float wB = vB ? __expf(evB - m) : 0.f;
        float evC = asC + adv; evC = evC >= 0.f ? evC : NEG_SLOPE * evC;
        const float wC = vC ? __expf(evC - m) : 0.f;
        float evD = asD + adv; evD = evD >= 0.f ? evD : NEG_SLOPE * evD;
        const float wD = vD ? __expf(evD - m) : 0.f;

        acc.x = fmaf(wA, bf2f(hA.x), acc.x);
        acc.y = fmaf(wA, bf2f(hA.y), acc.y);
        acc.z = fmaf(wA, bf2f(hA.z), acc.z);
        acc.w = fmaf(wA, bf2f(hA.w), acc.w);
        acc.x = fmaf(wB, bf2f(hB.x), acc.x);
        acc.y = fmaf(wB, bf2f(hB.y), acc.y);
        acc.z = fmaf(wB, bf2f(hB.z), acc.z);
        acc.w = fmaf(wB, bf2f(hB.w), acc.w);
        acc.x = fmaf(wC, bf2f(hC.x), acc.x);
        acc.y = fmaf(wC, bf2f(hC.y), acc.y);
        acc.z = fmaf(wC, bf2f(hC.z), acc.z);
        acc.w = fmaf(wC, bf2f(hC.w), acc.w);
        acc.x = fmaf(wD, bf2f(hD.x), acc.x);
        acc.y = fmaf(wD, bf2f(hD.y), acc.y);
        acc.z = fmaf(wD, bf2f(hD.z), acc.z);
        acc.w = fmaf(wD, bf2f(hD.w), acc.w);
        wsum += (wA + wB) + (wC + wD);
    }
#pragma unroll
    for (int off = 8; off < 64; off <<= 1) {
        acc.x += __shfl_xor(acc.x, off, 64);
        acc.y += __shfl_xor(acc.y, off, 64);
        acc.z += __shfl_xor(acc.z, off, 64);
        acc.w += __shfl_xor(acc.w, off, 64);
        wsum  += __shfl_xor(wsum, off, 64);
    }
    if (lane < 8) {
        const float inv = 1.f / (wsum + 1e-16f);
        float4 o; o.x = acc.x * inv; o.y = acc.y * inv; o.z = acc.z * inv; o.w = acc.w * inv;
        *(float4*)&out[(long long)n * 32 + lane * 4] = o;
    }
}

// ========== Fused gate MLP + per-graph max (replaces k_gate + k_gmax) ==========
// 8 chunks/graph; each 32-lane group computes gate for its nodes (same math as
// k_gate) and the block reduces a per-graph max -> 1 spread atomicMax per block.
__global__ __launch_bounds__(256) void k_gatemax(
    const float* __restrict__ out2, const float* __restrict__ b2,
    const float* __restrict__ gw1, const float* __restrict__ gb1,
    const float* __restrict__ gw2, const float* __restrict__ gb2,
    const int* __restrict__ gbound,
    float* __restrict__ gate, unsigned* __restrict__ gmax)
{
    const int g  = blockIdx.x >> 3;
    const int ch = blockIdx.x & 7;
    const int s0 = gbound[g], s1 = gbound[g + 1];
    const int len = s1 - s0;
    const int c0 = s0 + (int)(((long long)len * ch) >> 3);
    const int c1 = s0 + (int)(((long long)len * (ch + 1)) >> 3);

    const int c   = threadIdx.x & 31;
    const int grp = threadIdx.x >> 5;

    __shared__ float sred[4];

    float mloc = -INFINITY;
    for (int n = c0 + grp; n < c1; n += 8) {
        float v = out2[(long long)n * 32 + c] + b2[c];
        v = elu1f(v);
        float t1 = gb1[c];
#pragma unroll
        for (int k = 0; k < 32; k++) {
            float hk = __shfl(v, k, 32);
            t1 = fmaf(hk, gw1[k * 32 + c], t1);
        }
        t1 = fmaxf(t1, 0.f);
        float gv = t1 * gw2[c];
#pragma unroll
        for (int off = 16; off > 0; off >>= 1) gv += __shfl_xor(gv, off, 32);
        const float gval = gv + gb2[0];
        if (c == 0) gate[n] = gval;
        mloc = fmaxf(mloc, gval);
    }
#pragma unroll
    for (int off = 32; off > 0; off >>= 1) mloc = fmaxf(mloc, __shfl_xor(mloc, off, 64));
    if ((threadIdx.x & 63) == 0) sred[threadIdx.x >> 6] = mloc;
    __syncthreads();
    if (threadIdx.x == 0) {
        float m = fmaxf(fmaxf(sred[0], sred[1]), fmaxf(sred[2], sred[3]));
        if (m > -INFINITY) atomicMax(&gmax[g], fflip(m));
    }
}

// ========== Pool stage 2: per-chunk partial weighted sums (no atomics) ==========
__global__ __launch_bounds__(256) void k_pool3(
    const float* __restrict__ out2, const float* __restrict__ b2,
    const float* __restrict__ gate, const int* __restrict__ gbound,
    const unsigned* __restrict__ gmax, float* __restrict__ partials)
{
    const int g  = blockIdx.x >> 3;
    const int ch = blockIdx.x & 7;
    const int s0 = gbound[g], s1 = gbound[g + 1];
    const int len = s1 - s0;
    const int c0 = s0 + (int)(((long long)len * ch) >> 3);
    const int c1 = s0 + (int)(((long long)len * (ch + 1)) >> 3);

    const int c   = threadIdx.x & 31;
    const int grp = threadIdx.x >> 5;
    const float gm = funflip(gmax[g]);
    const float bc = b2[c];

    __shared__ float sacc[8][32];
    __shared__ float swsum[8];

    float acc = 0.f, wsum = 0.f;
    for (int n = c0 + grp; n < c1; n += 8) {
        float v = elu1f(out2[(long long)n * 32 + c] + bc);
        float ge = __expf(gate[n] - gm);
        acc = fmaf(ge, v, acc);
        wsum += ge;
    }
    sacc[grp][c] = acc;
    if (c == 0) swsum[grp] = wsum;
    __syncthreads();

    if (grp == 0) {
        float a = 0.f, wtot = 0.f;
#pragma unroll
        for (int i = 0; i < 8; i++) { a += sacc[i][c]; wtot += swsum[i]; }
        partials[(long long)blockIdx.x * 33 + c] = a;
        if (c == 0) partials[(long long)blockIdx.x * 33 + 32] = wtot;
    }
}

// ========== Pool stage 3: reduce 8 partials per graph, divide, write out ==========
__global__ __launch_bounds__(256) void k_pool4(
    const float* __restrict__ partials, float* __restrict__ out)
{
    const int g   = blockIdx.x;
    const int c   = threadIdx.x & 31;
    const int p   = threadIdx.x >> 5;

    __shared__ float sacc[8][32];
    __shared__ float swsum[8];

    sacc[p][c] = partials[(long long)(g * 8 + p) * 33 + c];
    if (c == 0) swsum[p] = partials[(long long)(g * 8 + p) * 33 + 32];
    __syncthreads();

    if (p == 0) {
        float a = 0.f, wtot = 0.f;
#pragma unroll
        for (int i = 0; i < 8; i++) { a += sacc[i][c]; wtot += swsum[i]; }
        out[g * 32 + c] = a / (wtot + 1e-16f);
    }
}

extern "C" void kernel_launch(void* const* d_in, const int* in_sizes, int n_in,
                              void* d_out, int out_size, void* d_ws, size_t ws_size,
                              hipStream_t stream)
{
    const float* x    = (const float*)d_in[0];
    const int*   ei   = (const int*)d_in[1];
    const int*   batch= (const int*)d_in[2];
    const float* W1   = (const float*)d_in[3];
    const float* as1w = (const float*)d_in[4];
    const float* ad1w = (const float*)d_in[5];
    const float* b1   = (const float*)d_in[6];
    const float* W2   = (const float*)d_in[7];
    const float* as2w = (const float*)d_in[8];
    const float* ad2w = (const float*)d_in[9];
    const float* b2   = (const float*)d_in[10];
    const float* gw1  = (const float*)d_in[11];
    const float* gb1  = (const float*)d_in[12];
    const float* gw2  = (const float*)d_in[13];
    const float* gb2  = (const float*)d_in[14];

    const int N  = in_sizes[2];
    const int E  = in_sizes[1] / 2;
    const int Et = E + N;
    const int G  = 64;
    const int nbk   = (N + BW - 1) >> BSH;   // 391 buckets (<=512)
    const int nchk  = (Et + 4095) / 4096;    // bucket-build chunks
    const int nblk1 = (N + 31) / 32;         // gemm1 blocks
    const int nblk2 = (N + 127) / 128;       // gemm2 blocks

    float* ws = (float*)d_ws;
    size_t o = 0;
    unsigned* ebuk = (unsigned*)(ws + o); o += (size_t)Et * 2;  // u32 used; +Et pad keeps h1 at the round-14 offset (measured lower FETCH)
    ushort* h1 = (ushort*)(ws + o); o += (size_t)N * 64;   // bf16 [N][128]
    ushort* out1 = (ushort*)(ws + o); o += (size_t)N * 64; // bf16 [N][128]
    ushort* h2 = (ushort*)(ws + o); o += (size_t)N * 16;   // bf16 [N][32]
    float* out2 = ws + o; o += (size_t)N * 32;
    float* asT1 = ws + o; o += (size_t)N * 4;              // [4][N] transposed
    float* a_d1 = ws + o; o += (size_t)N * 4;
    float* a_s2 = ws + o; o += (size_t)N;
    float* a_d2 = ws + o; o += (size_t)N;
    float* gate = ws + o; o += (size_t)N;
    int*   rowp = (int*)(ws + o); o += (size_t)N + 1;
    int*   esrc = (int*)(ws + o); o += (size_t)Et;
    int*   bbase= (int*)(ws + o); o += (size_t)nbk + 1;
    int*   bcur = (int*)(ws + o); o += (size_t)nbk;        // init by k_bscan
    int*   gbound = (int*)(ws + o); o += G + 1;
    float* partials = ws + o; o += (size_t)G * 8 * 33;
    // ---- zeroed region (one memset): bcnt + gmax + gmaxu + gmax2u ----
    size_t zstart = o;
    int*      bcnt   = (int*)(ws + o); o += (size_t)nbk;
    unsigned* gmax   = (unsigned*)(ws + o); o += G;
    unsigned* gmaxu  = (unsigned*)(ws + o); o += 4;        // layer-1 head maxes (flipped)
    unsigned* gmax2u = (unsigned*)(ws + o); o += 4;        // layer-2 max (flipped)
    size_t zbytes = (o - zstart) * sizeof(float);

    hipMemsetAsync(ws + zstart, 0, zbytes, stream);

    // ---- bucketed CSR build (shared by both layers) + graph bounds ----
    k_bcount  <<<nchk, 256, 0, stream>>>(ei, E, Et, nbk, bcnt);
    k_bscan   <<<1, 512, 0, stream>>>(bcnt, nbk, Et, bbase, bcur, batch, gbound, N, G);
    k_bscatter<<<nchk, 256, 0, stream>>>(ei, E, Et, nbk, bcur, ebuk);
    k_csr     <<<nbk, 256, 0, stream>>>(ebuk, bbase, N, Et, rowp, esrc);

    // ---- GAT layer 1 ----
    k_gemm1<<<nblk1, 256, 0, stream>>>(x, W1, as1w, ad1w, h1, asT1, a_d1, gmaxu, N);
    k_agg1 <<<(N + 3) / 4, 256, 0, stream>>>(rowp, esrc, asT1, a_d1, gmaxu, h1, out1, N);

    // ---- GAT layer 2 (elu(out1+b1) fused into gemm2 load) ----
    k_gemm2<<<nblk2, 256, 0, stream>>>(out1, W2, b1, as2w, ad2w, h2, a_s2, a_d2, gmax2u, N);
    k_agg2 <<<(N + 3) / 4, 256, 0, stream>>>(rowp, esrc, a_s2, a_d2, gmax2u, h2, out2, N);

    // ---- attentional pooling: fused gate+max, partial sums, final reduce ----
    k_gatemax<<<G * 8, 256, 0, stream>>>(out2, b2, gw1, gb1, gw2, gb2, gbound, gate, gmax);
    k_pool3  <<<G * 8, 256, 0, stream>>>(out2, b2, gate, gbound, gmax, partials);
    k_pool4  <<<G, 256, 0, stream>>>(partials, (float*)d_out);
}